// Round 5
// baseline (372.963 us; speedup 1.0000x reference)
//
#include <hip/hip_runtime.h>

#define BB 4
#define CC 256
#define HIDD 128
#define NN 4096

typedef short s8v __attribute__((ext_vector_type(8)));
typedef float f4v __attribute__((ext_vector_type(4)));
typedef unsigned short u16b;

static __device__ __forceinline__ float b2f(unsigned short u) {
    union { unsigned int i; float f; } v; v.i = ((unsigned int)u) << 16; return v.f;
}
static __device__ __forceinline__ unsigned short f2b(float f) {
    union { float f; unsigned int i; } v; v.f = f;
    unsigned int i = v.i;
    return (unsigned short)((i + 0x7fffu + ((i >> 16) & 1u)) >> 16);
}
// fp32 -> bf16 hi + bf16 lo (combined rel err ~2^-18)
static __device__ __forceinline__ void split2(float v, short& hi, short& lo) {
    unsigned short h = f2b(v);
    hi = (short)h;
    lo = (short)f2b(v - b2f(h));
}

// Standard swizzled fragment layout for 16x16x32 MFMA operands.
// Matrix logically [K x RC]; lane l of tile (kb,cb) holds j=0..7 at
// k = kb*32+(l>>4)*8+j, rc = cb*16+(l&15) -> one contiguous 16B run per lane.
__device__ __forceinline__ int swz(int k, int rc, int CB) {
    return (((k >> 5) * CB + (rc >> 4)) * 64 + ((k >> 3) & 3) * 16 + (rc & 15)) * 8 + (k & 7);
}
// Permuted swizzle for G': k-slot (q,j) <-> m_local = (j>>2)*16 + q*4 + (j&3).
// Matches the S^T C/D layout so the P A-fragment needs NO cross-lane transform.
__device__ __forceinline__ int gswz(int m, int o) {
    int kb = m >> 5, mm = m & 31;
    int qs = (mm >> 2) & 3;
    int js = ((mm >> 4) & 1) * 4 + (mm & 3);
    return ((kb * 8 + (o >> 4)) * 64 + qs * 16 + (o & 15)) * 8 + js;
}

// ---------- Phase 0: weights -> bf16 (theta/phi/mask split hi+lo, g plain) ------
__global__ __launch_bounds__(256) void prep_kernel(
    const float* __restrict__ wt, const float* __restrict__ wp,
    const float* __restrict__ wg, const float* __restrict__ wm,
    u16b* __restrict__ wHb, u16b* __restrict__ wLb, u16b* __restrict__ wgB,
    u16b* __restrict__ wmH, u16b* __restrict__ wmL)
{
    int t = blockIdx.x * 256 + threadIdx.x;   // grid 128 -> 32768 = HID*CC
    short h, l;
    split2(wt[t], h, l); wHb[t] = (u16b)h;           wLb[t] = (u16b)l;
    split2(wp[t], h, l); wHb[32768 + t] = (u16b)h;   wLb[32768 + t] = (u16b)l;
    wgB[t] = f2b(wg[t]);
    split2(wm[t], h, l); wmH[t] = (u16b)h;           wmL[t] = (u16b)l;
}

// ---------- Phase 1: Theta/Phi (split, swizzled) and G (plain, perm-swizzled) ---
// ot-halved: grid 512 (2 blocks/CU) for latency hiding; x loads duplicated 2x.
__global__ __launch_bounds__(256) void proj_kernel(
    const float* __restrict__ x, const u16b* __restrict__ wHb, const u16b* __restrict__ wLb,
    const u16b* __restrict__ wgB,
    u16b* __restrict__ thetaH, u16b* __restrict__ thetaL,
    u16b* __restrict__ phiH, u16b* __restrict__ phiL, u16b* __restrict__ gB)
{
    int wave = blockIdx.x * 4 + (threadIdx.x >> 6);   // 2048 waves
    int lane = threadIdx.x & 63;
    int l15 = lane & 15, q = lane >> 4;
    int b = wave >> 9;
    int rem = wave & 511;
    int ntile = rem >> 1;
    int half = rem & 1;                                // ot range half*4..half*4+3
    int n0 = ntile << 4;
    const float* xb = x + (size_t)b * CC * NN;

    f4v acc[3][4];
#pragma unroll
    for (int m = 0; m < 3; m++)
#pragma unroll
        for (int i = 0; i < 4; i++) acc[m][i] = (f4v){0.f, 0.f, 0.f, 0.f};

    for (int kc = 0; kc < 8; kc++) {
        int c0 = kc * 32;
        const float* xp = xb + (size_t)(c0 + q * 8) * NN + n0 + l15;
        s8v bh, bl;
#pragma unroll
        for (int j = 0; j < 8; j++) {
            short h, l;
            split2(xp[(size_t)j * NN], h, l);
            bh[j] = h; bl[j] = l;
        }
#pragma unroll
        for (int mat = 0; mat < 2; mat++) {
#pragma unroll
            for (int otl = 0; otl < 4; otl++) {
                int ot = half * 4 + otl;
                int woff = mat * 32768 + (ot * 16 + l15) * CC + c0 + q * 8;
                s8v ah = *reinterpret_cast<const s8v*>(wHb + woff);
                s8v al = *reinterpret_cast<const s8v*>(wLb + woff);
                acc[mat][otl] = __builtin_amdgcn_mfma_f32_16x16x32_bf16(ah, bh, acc[mat][otl], 0, 0, 0);
                acc[mat][otl] = __builtin_amdgcn_mfma_f32_16x16x32_bf16(ah, bl, acc[mat][otl], 0, 0, 0);
                acc[mat][otl] = __builtin_amdgcn_mfma_f32_16x16x32_bf16(al, bh, acc[mat][otl], 0, 0, 0);
            }
        }
#pragma unroll
        for (int otl = 0; otl < 4; otl++) {
            int ot = half * 4 + otl;
            const s8v* gw = reinterpret_cast<const s8v*>(wgB + (ot * 16 + l15) * CC + c0 + q * 8);
            acc[2][otl] = __builtin_amdgcn_mfma_f32_16x16x32_bf16(*gw, bh, acc[2][otl], 0, 0, 0);
        }
    }

    size_t boff = (size_t)b * (NN * HIDD);
#pragma unroll
    for (int otl = 0; otl < 4; otl++) {
#pragma unroll
        for (int r = 0; r < 4; r++) {
            int o = (half * 4 + otl) * 16 + q * 4 + r;   // C/D row (hid)
            int n = n0 + l15;                             // C/D col (spatial)
            int offTP = swz(o, n, NN / 16);
            short h, l;
            split2(acc[0][otl][r], h, l);
            thetaH[boff + offTP] = (u16b)h; thetaL[boff + offTP] = (u16b)l;
            split2(acc[1][otl][r], h, l);
            phiH[boff + offTP] = (u16b)h;   phiL[boff + offTP] = (u16b)l;
            gB[boff + gswz(n, o)] = f2b(acc[2][otl][r]);
        }
    }
}

// ---------- small path Phase 2: Lraw[m] = sum_n e^{s[n][m]} ---------------------
__global__ __launch_bounds__(256, 2) void stats_kernel(
    const u16b* __restrict__ thetaH, const u16b* __restrict__ thetaL,
    const u16b* __restrict__ phiH, const u16b* __restrict__ phiL,
    float* __restrict__ Lraw)
{
    int xcd = blockIdx.x & 7;                  // grid 1024
    int inner = blockIdx.x >> 3;               // 0..127
    int b = xcd >> 1;
    int su = (xcd & 1) * 128 + inner;          // 0..255 within batch
    int w = threadIdx.x >> 6;
    int wu = su * 4 + w;                       // 0..1023
    int mg = wu >> 4;                          // 64 groups of 4 mtiles
    int ns = wu & 15;                          // 16-way n-split
    int lane = threadIdx.x & 63;

    size_t boff = (size_t)b * (NN * HIDD);
    const u16b* thH = thetaH + boff; const u16b* thL = thetaL + boff;
    const u16b* phH = phiH + boff;   const u16b* phL = phiL + boff;

    s8v pBh[4][4], pBl[4][4];
#pragma unroll
    for (int mt = 0; mt < 4; mt++)
#pragma unroll
        for (int kb = 0; kb < 4; kb++) {
            int off = ((kb * 256 + (mg * 4 + mt)) * 64 + lane) * 8;
            pBh[mt][kb] = *reinterpret_cast<const s8v*>(phH + off);
            pBl[mt][kb] = *reinterpret_cast<const s8v*>(phL + off);
        }

    float Lp[4];
#pragma unroll
    for (int i = 0; i < 4; i++) Lp[i] = 0.f;

    for (int i = 0; i < 16; i++) {
        int ntile = ns * 16 + i;
        s8v tAh[4], tAl[4];
#pragma unroll
        for (int kb = 0; kb < 4; kb++) {
            int off = ((kb * 256 + ntile) * 64 + lane) * 8;
            tAh[kb] = *reinterpret_cast<const s8v*>(thH + off);
            tAl[kb] = *reinterpret_cast<const s8v*>(thL + off);
        }
#pragma unroll
        for (int mt = 0; mt < 4; mt++) {
            f4v shh = (f4v){0.f, 0.f, 0.f, 0.f};
            f4v sx  = (f4v){0.f, 0.f, 0.f, 0.f};
#pragma unroll
            for (int kb = 0; kb < 4; kb++)
                shh = __builtin_amdgcn_mfma_f32_16x16x32_bf16(tAh[kb], pBh[mt][kb], shh, 0, 0, 0);
#pragma unroll
            for (int kb = 0; kb < 4; kb++) {
                sx = __builtin_amdgcn_mfma_f32_16x16x32_bf16(tAh[kb], pBl[mt][kb], sx, 0, 0, 0);
                sx = __builtin_amdgcn_mfma_f32_16x16x32_bf16(tAl[kb], pBh[mt][kb], sx, 0, 0, 0);
            }
            Lp[mt] += (__expf(shh[0] + sx[0]) + __expf(shh[1] + sx[1]))
                    + (__expf(shh[2] + sx[2]) + __expf(shh[3] + sx[3]));
        }
    }
#pragma unroll
    for (int mt = 0; mt < 4; mt++) {
        float v = Lp[mt];
        v += __shfl_xor(v, 16);
        v += __shfl_xor(v, 32);
        if (lane < 16) atomicAdd(&Lraw[b * NN + (mg * 4 + mt) * 16 + lane], v);
    }
}

// ---------- Phase 2b: G'[m,o] = G[m,o] / L[m]  (in place, perm-swizzled) --------
__global__ __launch_bounds__(256) void rescale_kernel(
    u16b* __restrict__ gB, const float* __restrict__ Lraw)
{
    int t = blockIdx.x * 256 + threadIdx.x;    // grid 1024
    int flat0 = t * 8;
    int b = flat0 >> 19;
    int rem = flat0 & ((NN * HIDD) - 1);
    int kb = rem >> 12;
    int lane = (rem >> 3) & 63;
    int qs = lane >> 4;
    int mbase = kb * 32 + qs * 4;
    const float* Lp = Lraw + b * NN + mbase;
    u16b* gp = gB + flat0;
    s8v g = *reinterpret_cast<const s8v*>(gp);
    s8v o;
#pragma unroll
    for (int j = 0; j < 8; j++) {
        float v = b2f((unsigned short)g[j]) / Lp[((j >> 2) << 4) + (j & 3)];
        o[j] = (short)f2b(v);
    }
    *reinterpret_cast<s8v*>(gp) = o;
}

// ---------- small path Phase 3: Out += softmax(S) @ G', fused S^T recompute -----
__global__ __launch_bounds__(256, 2) void attn_kernel(
    const u16b* __restrict__ thetaH, const u16b* __restrict__ thetaL,
    const u16b* __restrict__ phiH, const u16b* __restrict__ phiL,
    const u16b* __restrict__ gB, float* __restrict__ outAcc)
{
    int xcd = blockIdx.x & 7;                  // grid 1024
    int inner = blockIdx.x >> 3;               // 0..127
    int combo = xcd * 4 + (inner & 3);         // 0..31 = b*8+ms (XCD-pinned)
    int b = combo >> 3;
    int ms = combo & 7;                        // 8-way m-split
    int ng = inner >> 2;                       // 0..31
    int w = threadIdx.x >> 6;
    int lane = threadIdx.x & 63;
    int l15 = lane & 15, q = lane >> 4;
    int ntile0 = ng * 8 + w * 2;

    size_t boff = (size_t)b * (NN * HIDD);
    const u16b* thH = thetaH + boff; const u16b* thL = thetaL + boff;
    const u16b* phH = phiH + boff;   const u16b* phL = phiL + boff;
    const u16b* gp = gB + boff;

    s8v tBh[2][4], tBl[2][4];
#pragma unroll
    for (int nt = 0; nt < 2; nt++)
#pragma unroll
        for (int kb = 0; kb < 4; kb++) {
            int off = ((kb * 256 + ntile0 + nt) * 64 + lane) * 8;
            tBh[nt][kb] = *reinterpret_cast<const s8v*>(thH + off);
            tBl[nt][kb] = *reinterpret_cast<const s8v*>(thL + off);
        }

    f4v acc[2][8];
#pragma unroll
    for (int nt = 0; nt < 2; nt++)
#pragma unroll
        for (int i = 0; i < 8; i++) acc[nt][i] = (f4v){0.f, 0.f, 0.f, 0.f};

    for (int mt = 0; mt < 16; mt++) {
        int m0 = ms * 512 + mt * 32;
        s8v pf[2];
#pragma unroll
        for (int h = 0; h < 2; h++) {
            int mtile = (m0 >> 4) + h;
            s8v pAh[4], pAl[4];
#pragma unroll
            for (int kb = 0; kb < 4; kb++) {
                int off = ((kb * 256 + mtile) * 64 + lane) * 8;
                pAh[kb] = *reinterpret_cast<const s8v*>(phH + off);
                pAl[kb] = *reinterpret_cast<const s8v*>(phL + off);
            }
#pragma unroll
            for (int nt = 0; nt < 2; nt++) {
                f4v shh = (f4v){0.f, 0.f, 0.f, 0.f};
                f4v sx  = (f4v){0.f, 0.f, 0.f, 0.f};
#pragma unroll
                for (int kb = 0; kb < 4; kb++)
                    shh = __builtin_amdgcn_mfma_f32_16x16x32_bf16(pAh[kb], tBh[nt][kb], shh, 0, 0, 0);
#pragma unroll
                for (int kb = 0; kb < 4; kb++) {
                    sx = __builtin_amdgcn_mfma_f32_16x16x32_bf16(pAh[kb], tBl[nt][kb], sx, 0, 0, 0);
                    sx = __builtin_amdgcn_mfma_f32_16x16x32_bf16(pAl[kb], tBh[nt][kb], sx, 0, 0, 0);
                }
#pragma unroll
                for (int r = 0; r < 4; r++)
                    pf[nt][h * 4 + r] = (short)f2b(__expf(shh[r] + sx[r]));
            }
        }
        int kb2 = m0 >> 5;
#pragma unroll
        for (int ot = 0; ot < 8; ot++) {
            s8v gf = *reinterpret_cast<const s8v*>(gp + ((kb2 * 8 + ot) * 64 + lane) * 8);
#pragma unroll
            for (int nt = 0; nt < 2; nt++)
                acc[nt][ot] = __builtin_amdgcn_mfma_f32_16x16x32_bf16(pf[nt], gf, acc[nt][ot], 0, 0, 0);
        }
    }

    float* oa = outAcc + (size_t)b * (NN * HIDD);
#pragma unroll
    for (int nt = 0; nt < 2; nt++) {
        int n_base = (ntile0 + nt) * 16;
#pragma unroll
        for (int ot = 0; ot < 8; ot++) {
#pragma unroll
            for (int r = 0; r < 4; r++) {
                int n = n_base + q * 4 + r;
                int o = ot * 16 + l15;
                atomicAdd(&oa[swz(o, n, NN / 16)], acc[nt][ot][r]);
            }
        }
    }
}

// ---------- big path Phase 2: S-pass -> P = e^s stored in A-frag layout ---------
// No accumulators, no atomics: m-split 16, grid 2048. One 16B store per nt.
__global__ __launch_bounds__(256, 2) void spass_kernel(
    const u16b* __restrict__ thetaH, const u16b* __restrict__ thetaL,
    const u16b* __restrict__ phiH, const u16b* __restrict__ phiL,
    u16b* __restrict__ P)
{
    int xcd = blockIdx.x & 7;                  // grid 2048
    int inner = blockIdx.x >> 3;               // 0..255
    int combo = xcd * 8 + (inner & 7);         // 0..63 = b*16+ms
    int b = combo >> 4;
    int ms = combo & 15;                       // 16-way m-split
    int ng = inner >> 3;                       // 0..31
    int w = threadIdx.x >> 6;
    int lane = threadIdx.x & 63;
    int ntile0 = ng * 8 + w * 2;

    size_t boff = (size_t)b * (NN * HIDD);
    const u16b* thH = thetaH + boff; const u16b* thL = thetaL + boff;
    const u16b* phH = phiH + boff;   const u16b* phL = phiL + boff;
    u16b* Pb = P + (size_t)b * NN * NN;

    s8v tBh[2][4], tBl[2][4];
#pragma unroll
    for (int nt = 0; nt < 2; nt++)
#pragma unroll
        for (int kb = 0; kb < 4; kb++) {
            int off = ((kb * 256 + ntile0 + nt) * 64 + lane) * 8;
            tBh[nt][kb] = *reinterpret_cast<const s8v*>(thH + off);
            tBl[nt][kb] = *reinterpret_cast<const s8v*>(thL + off);
        }

    for (int mt = 0; mt < 8; mt++) {
        int m0 = ms * 256 + mt * 32;
        s8v pf[2];
#pragma unroll
        for (int h = 0; h < 2; h++) {
            int mtile = (m0 >> 4) + h;
            s8v pAh[4], pAl[4];
#pragma unroll
            for (int kb = 0; kb < 4; kb++) {
                int off = ((kb * 256 + mtile) * 64 + lane) * 8;
                pAh[kb] = *reinterpret_cast<const s8v*>(phH + off);
                pAl[kb] = *reinterpret_cast<const s8v*>(phL + off);
            }
#pragma unroll
            for (int nt = 0; nt < 2; nt++) {
                f4v shh = (f4v){0.f, 0.f, 0.f, 0.f};
                f4v sx  = (f4v){0.f, 0.f, 0.f, 0.f};
#pragma unroll
                for (int kb = 0; kb < 4; kb++)
                    shh = __builtin_amdgcn_mfma_f32_16x16x32_bf16(pAh[kb], tBh[nt][kb], shh, 0, 0, 0);
#pragma unroll
                for (int kb = 0; kb < 4; kb++) {
                    sx = __builtin_amdgcn_mfma_f32_16x16x32_bf16(pAh[kb], tBl[nt][kb], sx, 0, 0, 0);
                    sx = __builtin_amdgcn_mfma_f32_16x16x32_bf16(pAl[kb], tBh[nt][kb], sx, 0, 0, 0);
                }
#pragma unroll
                for (int r = 0; r < 4; r++)
                    pf[nt][h * 4 + r] = (short)f2b(__expf(shh[r] + sx[r]));
            }
        }
        int kb2 = m0 >> 5;
#pragma unroll
        for (int nt = 0; nt < 2; nt++)
            *reinterpret_cast<s8v*>(Pb + ((size_t)(kb2 * 256 + ntile0 + nt) * 64 + lane) * 8) = pf[nt];
    }
}

// ---------- big path Phase 2a: L[m] = sum_n P[n,m] (from bf16-rounded P) --------
__global__ __launch_bounds__(256) void lreduce_kernel(
    const u16b* __restrict__ P, float* __restrict__ Lraw)
{
    int wv = blockIdx.x * 4 + (threadIdx.x >> 6);   // grid 512 -> 2048 waves
    int lane = threadIdx.x & 63;
    int l15 = lane & 15, q = lane >> 4;
    int b = wv >> 9;
    int rem = wv & 511;
    int kb2 = rem >> 2;                        // 0..127 (32-m block)
    int qt = rem & 3;                          // nt quarter
    const u16b* Pb = P + (size_t)b * NN * NN;

    float sum[8];
#pragma unroll
    for (int j = 0; j < 8; j++) sum[j] = 0.f;

    for (int i = 0; i < 64; i++) {
        int nt = qt * 64 + i;
        s8v p = *reinterpret_cast<const s8v*>(Pb + ((size_t)(kb2 * 256 + nt) * 64 + lane) * 8);
#pragma unroll
        for (int j = 0; j < 8; j++) sum[j] += b2f((unsigned short)p[j]);
    }
#pragma unroll
    for (int j = 0; j < 8; j++) {
        sum[j] += __shfl_xor(sum[j], 1);
        sum[j] += __shfl_xor(sum[j], 2);
        sum[j] += __shfl_xor(sum[j], 4);
        sum[j] += __shfl_xor(sum[j], 8);
    }
    if (l15 == 0) {
#pragma unroll
        for (int j = 0; j < 8; j++) {
            int m = kb2 * 32 + q * 4 + (j & 3) + ((j >> 2) << 4);
            atomicAdd(&Lraw[b * NN + m], sum[j]);
        }
    }
}

// ---------- big path Phase 3: Out += P @ G' (pure GEMM, no exp) -----------------
__global__ __launch_bounds__(256, 2) void pv_kernel(
    const u16b* __restrict__ P, const u16b* __restrict__ gB, float* __restrict__ outAcc)
{
    int xcd = blockIdx.x & 7;                  // grid 1024
    int inner = blockIdx.x >> 3;               // 0..127
    int combo = xcd * 4 + (inner & 3);         // 0..31 = b*8+ms
    int b = combo >> 3;
    int ms = combo & 7;
    int ng = inner >> 2;                       // 0..31
    int w = threadIdx.x >> 6;
    int lane = threadIdx.x & 63;
    int l15 = lane & 15, q = lane >> 4;
    int ntile0 = ng * 8 + w * 2;

    const u16b* Pb = P + (size_t)b * NN * NN;
    const u16b* gp = gB + (size_t)b * (NN * HIDD);

    f4v acc[2][8];
#pragma unroll
    for (int nt = 0; nt < 2; nt++)
#pragma unroll
        for (int i = 0; i < 8; i++) acc[nt][i] = (f4v){0.f, 0.f, 0.f, 0.f};

    for (int mt = 0; mt < 16; mt++) {
        int kb2 = ms * 16 + mt;
        s8v pfr[2];
#pragma unroll
        for (int nt = 0; nt < 2; nt++)
            pfr[nt] = *reinterpret_cast<const s8v*>(Pb + ((size_t)(kb2 * 256 + ntile0 + nt) * 64 + lane) * 8);
#pragma unroll
        for (int ot = 0; ot < 8; ot++) {
            s8v gf = *reinterpret_cast<const s8v*>(gp + ((kb2 * 8 + ot) * 64 + lane) * 8);
#pragma unroll
            for (int nt = 0; nt < 2; nt++)
                acc[nt][ot] = __builtin_amdgcn_mfma_f32_16x16x32_bf16(pfr[nt], gf, acc[nt][ot], 0, 0, 0);
        }
    }

    float* oa = outAcc + (size_t)b * (NN * HIDD);
#pragma unroll
    for (int nt = 0; nt < 2; nt++) {
        int n_base = (ntile0 + nt) * 16;
#pragma unroll
        for (int ot = 0; ot < 8; ot++) {
#pragma unroll
            for (int r = 0; r < 4; r++) {
                int n = n_base + q * 4 + r;
                int o = ot * 16 + l15;
                atomicAdd(&oa[swz(o, n, NN / 16)], acc[nt][ot][r]);
            }
        }
    }
}

// ---------- Phase 4: y = x + w_mask @ Out^T (split path: mask is ~450-scale) ----
__global__ __launch_bounds__(256) void final_kernel(
    const float* __restrict__ x, const u16b* __restrict__ wmH, const u16b* __restrict__ wmL,
    const float* __restrict__ outAcc, float* __restrict__ y)
{
    int wave = blockIdx.x * 4 + (threadIdx.x >> 6);   // 4096 waves
    int lane = threadIdx.x & 63;
    int l15 = lane & 15, q = lane >> 4;
    int b = wave >> 10;
    int rem = wave & 1023;
    int ctile = rem >> 6;
    int n64 = rem & 63;
    const float* oa = outAcc + (size_t)b * (NN * HIDD);
    const float* xb = x + (size_t)b * CC * NN;
    float* yb = y + (size_t)b * CC * NN;
    int c0 = ctile * 16;

    s8v aH[4], aL[4];
#pragma unroll
    for (int kb = 0; kb < 4; kb++) {
        int off = (c0 + l15) * HIDD + kb * 32 + q * 8;
        aH[kb] = *reinterpret_cast<const s8v*>(wmH + off);
        aL[kb] = *reinterpret_cast<const s8v*>(wmL + off);
    }

#pragma unroll
    for (int nt = 0; nt < 4; nt++) {
        int ntile = n64 * 4 + nt;
        f4v acc = (f4v){0.f, 0.f, 0.f, 0.f};
#pragma unroll
        for (int kb = 0; kb < 4; kb++) {
            const float* bp = oa + ((size_t)(kb * 256 + ntile) * 64 + lane) * 8;
            f4v b0 = *reinterpret_cast<const f4v*>(bp);
            f4v b1 = *reinterpret_cast<const f4v*>(bp + 4);
            s8v bhv, blv;
#pragma unroll
            for (int j = 0; j < 4; j++) {
                short h, l;
                split2(b0[j], h, l); bhv[j] = h; blv[j] = l;
                split2(b1[j], h, l); bhv[j + 4] = h; blv[j + 4] = l;
            }
            acc = __builtin_amdgcn_mfma_f32_16x16x32_bf16(aH[kb], bhv, acc, 0, 0, 0);
            acc = __builtin_amdgcn_mfma_f32_16x16x32_bf16(aH[kb], blv, acc, 0, 0, 0);
            acc = __builtin_amdgcn_mfma_f32_16x16x32_bf16(aL[kb], bhv, acc, 0, 0, 0);
        }
#pragma unroll
        for (int r = 0; r < 4; r++) {
            int c = c0 + q * 4 + r;
            int n = ntile * 16 + l15;
            size_t idx = (size_t)c * NN + n;
            yb[idx] = xb[idx] + acc[r];
        }
    }
}

extern "C" void kernel_launch(void* const* d_in, const int* in_sizes, int n_in,
                              void* d_out, int out_size, void* d_ws, size_t ws_size,
                              hipStream_t stream)
{
    (void)in_sizes; (void)n_in; (void)out_size;
    const float* x  = (const float*)d_in[0];
    const float* wt = (const float*)d_in[1];
    const float* wp = (const float*)d_in[2];
    const float* wg = (const float*)d_in[3];
    const float* wm = (const float*)d_in[4];
    float* y = (float*)d_out;

    char* ws = (char*)d_ws;
    const size_t MB = 1 << 20;
    u16b* thetaH = (u16b*)(ws + 0 * MB);
    u16b* thetaL = (u16b*)(ws + 4 * MB);
    u16b* phiH   = (u16b*)(ws + 8 * MB);
    u16b* phiL   = (u16b*)(ws + 12 * MB);
    u16b* gB     = (u16b*)(ws + 16 * MB);
    float* outAcc = (float*)(ws + 20 * MB);                // 8 MB fp32
    float* Lraw   = (float*)(ws + 28 * MB);                // 64 KB
    char* wbase = ws + 28 * MB + (64 << 10);
    u16b* wHb = (u16b*)(wbase);                            // 128 KB
    u16b* wLb = (u16b*)(wbase + (128 << 10));              // 128 KB
    u16b* wgB = (u16b*)(wbase + (256 << 10));              // 64 KB
    u16b* wmH = (u16b*)(wbase + (320 << 10));              // 64 KB
    u16b* wmL = (u16b*)(wbase + (384 << 10));              // 64 KB
    u16b* P   = (u16b*)(ws + 32 * MB);                     // 134.2 MB (big path)

    const size_t need_big = 32 * MB + (size_t)BB * NN * NN * sizeof(u16b);  // 160 MB
    const bool big = ws_size >= need_big;

    hipMemsetAsync(outAcc, 0, (size_t)BB * NN * HIDD * sizeof(float), stream);
    hipMemsetAsync(Lraw, 0, (size_t)BB * NN * sizeof(float), stream);

    hipLaunchKernelGGL(prep_kernel, dim3(128), dim3(256), 0, stream,
                       wt, wp, wg, wm, wHb, wLb, wgB, wmH, wmL);
    hipLaunchKernelGGL(proj_kernel, dim3(512), dim3(256), 0, stream,
                       x, wHb, wLb, wgB, thetaH, thetaL, phiH, phiL, gB);

    if (big) {
        hipLaunchKernelGGL(spass_kernel,   dim3(2048), dim3(256), 0, stream,
                           thetaH, thetaL, phiH, phiL, P);
        hipLaunchKernelGGL(lreduce_kernel, dim3(512),  dim3(256), 0, stream, P, Lraw);
        hipLaunchKernelGGL(rescale_kernel, dim3(1024), dim3(256), 0, stream, gB, Lraw);
        hipLaunchKernelGGL(pv_kernel,      dim3(1024), dim3(256), 0, stream, P, gB, outAcc);
    } else {
        hipLaunchKernelGGL(stats_kernel,   dim3(1024), dim3(256), 0, stream,
                           thetaH, thetaL, phiH, phiL, Lraw);
        hipLaunchKernelGGL(rescale_kernel, dim3(1024), dim3(256), 0, stream, gB, Lraw);
        hipLaunchKernelGGL(attn_kernel,    dim3(1024), dim3(256), 0, stream,
                           thetaH, thetaL, phiH, phiL, gB, outAcc);
    }
    hipLaunchKernelGGL(final_kernel, dim3(1024), dim3(256), 0, stream,
                       x, wmH, wmL, outAcc, y);
}

// Round 6
// 259.351 us; speedup vs baseline: 1.4381x; 1.4381x over previous
//
#include <hip/hip_runtime.h>

#define BB 4
#define CC 256
#define HIDD 128
#define NN 4096

typedef short s8v __attribute__((ext_vector_type(8)));
typedef float f4v __attribute__((ext_vector_type(4)));
typedef unsigned short u16b;

static __device__ __forceinline__ float b2f(unsigned short u) {
    union { unsigned int i; float f; } v; v.i = ((unsigned int)u) << 16; return v.f;
}
static __device__ __forceinline__ unsigned short f2b(float f) {
    union { float f; unsigned int i; } v; v.f = f;
    unsigned int i = v.i;
    return (unsigned short)((i + 0x7fffu + ((i >> 16) & 1u)) >> 16);
}
// fp32 -> bf16 hi + bf16 lo (combined rel err ~2^-18)
static __device__ __forceinline__ void split2(float v, short& hi, short& lo) {
    unsigned short h = f2b(v);
    hi = (short)h;
    lo = (short)f2b(v - b2f(h));
}

// Standard swizzled fragment layout for 16x16x32 MFMA operands.
// Matrix logically [K x RC]; lane l of tile (kb,cb) holds j=0..7 at
// k = kb*32+(l>>4)*8+j, rc = cb*16+(l&15) -> one contiguous 16B run per lane.
__device__ __forceinline__ int swz(int k, int rc, int CB) {
    return (((k >> 5) * CB + (rc >> 4)) * 64 + ((k >> 3) & 3) * 16 + (rc & 15)) * 8 + (k & 7);
}
// Permuted swizzle for G': k-slot (q,j) <-> m_local = (j>>2)*16 + q*4 + (j&3).
// Matches the S^T C/D layout so the P A-fragment needs NO cross-lane transform.
__device__ __forceinline__ int gswz(int m, int o) {
    int kb = m >> 5, mm = m & 31;
    int qs = (mm >> 2) & 3;
    int js = ((mm >> 4) & 1) * 4 + (mm & 3);
    return ((kb * 8 + (o >> 4)) * 64 + qs * 16 + (o & 15)) * 8 + js;
}

// ---------- Phase 0: weights -> bf16 (theta/phi/mask split hi+lo, g plain) ------
__global__ __launch_bounds__(256) void prep_kernel(
    const float* __restrict__ wt, const float* __restrict__ wp,
    const float* __restrict__ wg, const float* __restrict__ wm,
    u16b* __restrict__ wHb, u16b* __restrict__ wLb, u16b* __restrict__ wgB,
    u16b* __restrict__ wmH, u16b* __restrict__ wmL)
{
    int t = blockIdx.x * 256 + threadIdx.x;   // grid 128 -> 32768 = HID*CC
    short h, l;
    split2(wt[t], h, l); wHb[t] = (u16b)h;           wLb[t] = (u16b)l;
    split2(wp[t], h, l); wHb[32768 + t] = (u16b)h;   wLb[32768 + t] = (u16b)l;
    wgB[t] = f2b(wg[t]);
    split2(wm[t], h, l); wmH[t] = (u16b)h;           wmL[t] = (u16b)l;
}

// ---------- Phase 1: Theta/Phi (split, swizzled) and G (plain, perm-swizzled) ---
__global__ __launch_bounds__(256) void proj_kernel(
    const float* __restrict__ x, const u16b* __restrict__ wHb, const u16b* __restrict__ wLb,
    const u16b* __restrict__ wgB,
    u16b* __restrict__ thetaH, u16b* __restrict__ thetaL,
    u16b* __restrict__ phiH, u16b* __restrict__ phiL, u16b* __restrict__ gB)
{
    int wave = blockIdx.x * 4 + (threadIdx.x >> 6);   // 2048 waves
    int lane = threadIdx.x & 63;
    int l15 = lane & 15, q = lane >> 4;
    int b = wave >> 9;
    int rem = wave & 511;
    int ntile = rem >> 1;
    int half = rem & 1;                                // ot range half*4..half*4+3
    int n0 = ntile << 4;
    const float* xb = x + (size_t)b * CC * NN;

    f4v acc[3][4];
#pragma unroll
    for (int m = 0; m < 3; m++)
#pragma unroll
        for (int i = 0; i < 4; i++) acc[m][i] = (f4v){0.f, 0.f, 0.f, 0.f};

    for (int kc = 0; kc < 8; kc++) {
        int c0 = kc * 32;
        const float* xp = xb + (size_t)(c0 + q * 8) * NN + n0 + l15;
        s8v bh, bl;
#pragma unroll
        for (int j = 0; j < 8; j++) {
            short h, l;
            split2(xp[(size_t)j * NN], h, l);
            bh[j] = h; bl[j] = l;
        }
#pragma unroll
        for (int mat = 0; mat < 2; mat++) {
#pragma unroll
            for (int otl = 0; otl < 4; otl++) {
                int ot = half * 4 + otl;
                int woff = mat * 32768 + (ot * 16 + l15) * CC + c0 + q * 8;
                s8v ah = *reinterpret_cast<const s8v*>(wHb + woff);
                s8v al = *reinterpret_cast<const s8v*>(wLb + woff);
                acc[mat][otl] = __builtin_amdgcn_mfma_f32_16x16x32_bf16(ah, bh, acc[mat][otl], 0, 0, 0);
                acc[mat][otl] = __builtin_amdgcn_mfma_f32_16x16x32_bf16(ah, bl, acc[mat][otl], 0, 0, 0);
                acc[mat][otl] = __builtin_amdgcn_mfma_f32_16x16x32_bf16(al, bh, acc[mat][otl], 0, 0, 0);
            }
        }
#pragma unroll
        for (int otl = 0; otl < 4; otl++) {
            int ot = half * 4 + otl;
            const s8v* gw = reinterpret_cast<const s8v*>(wgB + (ot * 16 + l15) * CC + c0 + q * 8);
            acc[2][otl] = __builtin_amdgcn_mfma_f32_16x16x32_bf16(*gw, bh, acc[2][otl], 0, 0, 0);
        }
    }

    size_t boff = (size_t)b * (NN * HIDD);
#pragma unroll
    for (int otl = 0; otl < 4; otl++) {
#pragma unroll
        for (int r = 0; r < 4; r++) {
            int o = (half * 4 + otl) * 16 + q * 4 + r;   // C/D row (hid)
            int n = n0 + l15;                             // C/D col (spatial)
            int offTP = swz(o, n, NN / 16);
            short h, l;
            split2(acc[0][otl][r], h, l);
            thetaH[boff + offTP] = (u16b)h; thetaL[boff + offTP] = (u16b)l;
            split2(acc[1][otl][r], h, l);
            phiH[boff + offTP] = (u16b)h;   phiL[boff + offTP] = (u16b)l;
            gB[boff + gswz(n, o)] = f2b(acc[2][otl][r]);
        }
    }
}

// ---------- small path Phase 2: Lraw[m] = sum_n e^{s[n][m]} ---------------------
__global__ __launch_bounds__(256, 2) void stats_kernel(
    const u16b* __restrict__ thetaH, const u16b* __restrict__ thetaL,
    const u16b* __restrict__ phiH, const u16b* __restrict__ phiL,
    float* __restrict__ Lraw)
{
    int xcd = blockIdx.x & 7;                  // grid 1024
    int inner = blockIdx.x >> 3;               // 0..127
    int b = xcd >> 1;
    int su = (xcd & 1) * 128 + inner;          // 0..255 within batch
    int w = threadIdx.x >> 6;
    int wu = su * 4 + w;                       // 0..1023
    int mg = wu >> 4;                          // 64 groups of 4 mtiles
    int ns = wu & 15;                          // 16-way n-split
    int lane = threadIdx.x & 63;

    size_t boff = (size_t)b * (NN * HIDD);
    const u16b* thH = thetaH + boff; const u16b* thL = thetaL + boff;
    const u16b* phH = phiH + boff;   const u16b* phL = phiL + boff;

    s8v pBh[4][4], pBl[4][4];
#pragma unroll
    for (int mt = 0; mt < 4; mt++)
#pragma unroll
        for (int kb = 0; kb < 4; kb++) {
            int off = ((kb * 256 + (mg * 4 + mt)) * 64 + lane) * 8;
            pBh[mt][kb] = *reinterpret_cast<const s8v*>(phH + off);
            pBl[mt][kb] = *reinterpret_cast<const s8v*>(phL + off);
        }

    float Lp[4];
#pragma unroll
    for (int i = 0; i < 4; i++) Lp[i] = 0.f;

    for (int i = 0; i < 16; i++) {
        int ntile = ns * 16 + i;
        s8v tAh[4], tAl[4];
#pragma unroll
        for (int kb = 0; kb < 4; kb++) {
            int off = ((kb * 256 + ntile) * 64 + lane) * 8;
            tAh[kb] = *reinterpret_cast<const s8v*>(thH + off);
            tAl[kb] = *reinterpret_cast<const s8v*>(thL + off);
        }
#pragma unroll
        for (int mt = 0; mt < 4; mt++) {
            f4v shh = (f4v){0.f, 0.f, 0.f, 0.f};
            f4v sx  = (f4v){0.f, 0.f, 0.f, 0.f};
#pragma unroll
            for (int kb = 0; kb < 4; kb++)
                shh = __builtin_amdgcn_mfma_f32_16x16x32_bf16(tAh[kb], pBh[mt][kb], shh, 0, 0, 0);
#pragma unroll
            for (int kb = 0; kb < 4; kb++) {
                sx = __builtin_amdgcn_mfma_f32_16x16x32_bf16(tAh[kb], pBl[mt][kb], sx, 0, 0, 0);
                sx = __builtin_amdgcn_mfma_f32_16x16x32_bf16(tAl[kb], pBh[mt][kb], sx, 0, 0, 0);
            }
            Lp[mt] += (__expf(shh[0] + sx[0]) + __expf(shh[1] + sx[1]))
                    + (__expf(shh[2] + sx[2]) + __expf(shh[3] + sx[3]));
        }
    }
#pragma unroll
    for (int mt = 0; mt < 4; mt++) {
        float v = Lp[mt];
        v += __shfl_xor(v, 16);
        v += __shfl_xor(v, 32);
        if (lane < 16) atomicAdd(&Lraw[b * NN + (mg * 4 + mt) * 16 + lane], v);
    }
}

// ---------- Phase 2b: G'[m,o] = G[m,o] / L[m]  (in place, perm-swizzled) --------
__global__ __launch_bounds__(256) void rescale_kernel(
    u16b* __restrict__ gB, const float* __restrict__ Lraw)
{
    int t = blockIdx.x * 256 + threadIdx.x;    // grid 1024
    int flat0 = t * 8;
    int b = flat0 >> 19;
    int rem = flat0 & ((NN * HIDD) - 1);
    int kb = rem >> 12;
    int lane = (rem >> 3) & 63;
    int qs = lane >> 4;
    int mbase = kb * 32 + qs * 4;
    const float* Lp = Lraw + b * NN + mbase;
    u16b* gp = gB + flat0;
    s8v g = *reinterpret_cast<const s8v*>(gp);
    s8v o;
#pragma unroll
    for (int j = 0; j < 8; j++) {
        float v = b2f((unsigned short)g[j]) / Lp[((j >> 2) << 4) + (j & 3)];
        o[j] = (short)f2b(v);
    }
    *reinterpret_cast<s8v*>(gp) = o;
}

// ---------- small path Phase 3: Out += softmax(S) @ G', fused S^T recompute -----
__global__ __launch_bounds__(256, 2) void attn_kernel(
    const u16b* __restrict__ thetaH, const u16b* __restrict__ thetaL,
    const u16b* __restrict__ phiH, const u16b* __restrict__ phiL,
    const u16b* __restrict__ gB, float* __restrict__ outAcc)
{
    int xcd = blockIdx.x & 7;                  // grid 1024
    int inner = blockIdx.x >> 3;               // 0..127
    int combo = xcd * 4 + (inner & 3);         // 0..31 = b*8+ms (XCD-pinned)
    int b = combo >> 3;
    int ms = combo & 7;                        // 8-way m-split
    int ng = inner >> 2;                       // 0..31
    int w = threadIdx.x >> 6;
    int lane = threadIdx.x & 63;
    int l15 = lane & 15, q = lane >> 4;
    int ntile0 = ng * 8 + w * 2;

    size_t boff = (size_t)b * (NN * HIDD);
    const u16b* thH = thetaH + boff; const u16b* thL = thetaL + boff;
    const u16b* phH = phiH + boff;   const u16b* phL = phiL + boff;
    const u16b* gp = gB + boff;

    s8v tBh[2][4], tBl[2][4];
#pragma unroll
    for (int nt = 0; nt < 2; nt++)
#pragma unroll
        for (int kb = 0; kb < 4; kb++) {
            int off = ((kb * 256 + ntile0 + nt) * 64 + lane) * 8;
            tBh[nt][kb] = *reinterpret_cast<const s8v*>(thH + off);
            tBl[nt][kb] = *reinterpret_cast<const s8v*>(thL + off);
        }

    f4v acc[2][8];
#pragma unroll
    for (int nt = 0; nt < 2; nt++)
#pragma unroll
        for (int i = 0; i < 8; i++) acc[nt][i] = (f4v){0.f, 0.f, 0.f, 0.f};

    for (int mt = 0; mt < 16; mt++) {
        int m0 = ms * 512 + mt * 32;
        s8v pf[2];
#pragma unroll
        for (int h = 0; h < 2; h++) {
            int mtile = (m0 >> 4) + h;
            s8v pAh[4], pAl[4];
#pragma unroll
            for (int kb = 0; kb < 4; kb++) {
                int off = ((kb * 256 + mtile) * 64 + lane) * 8;
                pAh[kb] = *reinterpret_cast<const s8v*>(phH + off);
                pAl[kb] = *reinterpret_cast<const s8v*>(phL + off);
            }
#pragma unroll
            for (int nt = 0; nt < 2; nt++) {
                f4v shh = (f4v){0.f, 0.f, 0.f, 0.f};
                f4v sx  = (f4v){0.f, 0.f, 0.f, 0.f};
#pragma unroll
                for (int kb = 0; kb < 4; kb++)
                    shh = __builtin_amdgcn_mfma_f32_16x16x32_bf16(pAh[kb], tBh[nt][kb], shh, 0, 0, 0);
#pragma unroll
                for (int kb = 0; kb < 4; kb++) {
                    sx = __builtin_amdgcn_mfma_f32_16x16x32_bf16(pAh[kb], tBl[nt][kb], sx, 0, 0, 0);
                    sx = __builtin_amdgcn_mfma_f32_16x16x32_bf16(pAl[kb], tBh[nt][kb], sx, 0, 0, 0);
                }
#pragma unroll
                for (int r = 0; r < 4; r++)
                    pf[nt][h * 4 + r] = (short)f2b(__expf(shh[r] + sx[r]));
            }
        }
        int kb2 = m0 >> 5;
#pragma unroll
        for (int ot = 0; ot < 8; ot++) {
            s8v gf = *reinterpret_cast<const s8v*>(gp + ((kb2 * 8 + ot) * 64 + lane) * 8);
#pragma unroll
            for (int nt = 0; nt < 2; nt++)
                acc[nt][ot] = __builtin_amdgcn_mfma_f32_16x16x32_bf16(pf[nt], gf, acc[nt][ot], 0, 0, 0);
        }
    }

    float* oa = outAcc + (size_t)b * (NN * HIDD);
#pragma unroll
    for (int nt = 0; nt < 2; nt++) {
        int n_base = (ntile0 + nt) * 16;
#pragma unroll
        for (int ot = 0; ot < 8; ot++) {
#pragma unroll
            for (int r = 0; r < 4; r++) {
                int n = n_base + q * 4 + r;
                int o = ot * 16 + l15;
                atomicAdd(&oa[swz(o, n, NN / 16)], acc[nt][ot][r]);
            }
        }
    }
}

// ---------- big path Phase 2: S-pass -> P = e^s stored in A-frag layout ---------
// mt iteration staggered by block to decorrelate same-address phi loads.
__global__ __launch_bounds__(256, 2) void spass_kernel(
    const u16b* __restrict__ thetaH, const u16b* __restrict__ thetaL,
    const u16b* __restrict__ phiH, const u16b* __restrict__ phiL,
    u16b* __restrict__ P)
{
    int xcd = blockIdx.x & 7;                  // grid 2048
    int inner = blockIdx.x >> 3;               // 0..255
    int combo = xcd * 8 + (inner & 7);         // 0..63 = b*16+ms
    int b = combo >> 4;
    int ms = combo & 15;                       // 16-way m-split
    int ng = inner >> 3;                       // 0..31
    int w = threadIdx.x >> 6;
    int lane = threadIdx.x & 63;
    int ntile0 = ng * 8 + w * 2;

    size_t boff = (size_t)b * (NN * HIDD);
    const u16b* thH = thetaH + boff; const u16b* thL = thetaL + boff;
    const u16b* phH = phiH + boff;   const u16b* phL = phiL + boff;
    u16b* Pb = P + (size_t)b * NN * NN;

    s8v tBh[2][4], tBl[2][4];
#pragma unroll
    for (int nt = 0; nt < 2; nt++)
#pragma unroll
        for (int kb = 0; kb < 4; kb++) {
            int off = ((kb * 256 + ntile0 + nt) * 64 + lane) * 8;
            tBh[nt][kb] = *reinterpret_cast<const s8v*>(thH + off);
            tBl[nt][kb] = *reinterpret_cast<const s8v*>(thL + off);
        }

    int ph = ng & 7;                           // stagger phase
    for (int mt = 0; mt < 8; mt++) {
        int mtr = (mt + ph) & 7;
        int m0 = ms * 256 + mtr * 32;
        s8v pf[2];
#pragma unroll
        for (int h = 0; h < 2; h++) {
            int mtile = (m0 >> 4) + h;
            s8v pAh[4], pAl[4];
#pragma unroll
            for (int kb = 0; kb < 4; kb++) {
                int off = ((kb * 256 + mtile) * 64 + lane) * 8;
                pAh[kb] = *reinterpret_cast<const s8v*>(phH + off);
                pAl[kb] = *reinterpret_cast<const s8v*>(phL + off);
            }
#pragma unroll
            for (int nt = 0; nt < 2; nt++) {
                f4v shh = (f4v){0.f, 0.f, 0.f, 0.f};
                f4v sx  = (f4v){0.f, 0.f, 0.f, 0.f};
#pragma unroll
                for (int kb = 0; kb < 4; kb++)
                    shh = __builtin_amdgcn_mfma_f32_16x16x32_bf16(pAh[kb], tBh[nt][kb], shh, 0, 0, 0);
#pragma unroll
                for (int kb = 0; kb < 4; kb++) {
                    sx = __builtin_amdgcn_mfma_f32_16x16x32_bf16(pAh[kb], tBl[nt][kb], sx, 0, 0, 0);
                    sx = __builtin_amdgcn_mfma_f32_16x16x32_bf16(pAl[kb], tBh[nt][kb], sx, 0, 0, 0);
                }
#pragma unroll
                for (int r = 0; r < 4; r++)
                    pf[nt][h * 4 + r] = (short)f2b(__expf(shh[r] + sx[r]));
            }
        }
        int kb2 = m0 >> 5;
#pragma unroll
        for (int nt = 0; nt < 2; nt++)
            *reinterpret_cast<s8v*>(Pb + ((size_t)(kb2 * 256 + ntile0 + nt) * 64 + lane) * 8) = pf[nt];
    }
}

// ---------- big path Phase 2a: L[m] = sum_n P[n,m] (from bf16-rounded P) --------
__global__ __launch_bounds__(256) void lreduce_kernel(
    const u16b* __restrict__ P, float* __restrict__ Lraw)
{
    int wv = blockIdx.x * 4 + (threadIdx.x >> 6);   // grid 512 -> 2048 waves
    int lane = threadIdx.x & 63;
    int l15 = lane & 15, q = lane >> 4;
    int b = wv >> 9;
    int rem = wv & 511;
    int kb2 = rem >> 2;                        // 0..127 (32-m block)
    int qt = rem & 3;                          // nt quarter
    const u16b* Pb = P + (size_t)b * NN * NN;

    float sum[8];
#pragma unroll
    for (int j = 0; j < 8; j++) sum[j] = 0.f;

    for (int i = 0; i < 64; i++) {
        int nt = qt * 64 + i;
        s8v p = *reinterpret_cast<const s8v*>(Pb + ((size_t)(kb2 * 256 + nt) * 64 + lane) * 8);
#pragma unroll
        for (int j = 0; j < 8; j++) sum[j] += b2f((unsigned short)p[j]);
    }
#pragma unroll
    for (int j = 0; j < 8; j++) {
        sum[j] += __shfl_xor(sum[j], 1);
        sum[j] += __shfl_xor(sum[j], 2);
        sum[j] += __shfl_xor(sum[j], 4);
        sum[j] += __shfl_xor(sum[j], 8);
    }
    if (l15 == 0) {
#pragma unroll
        for (int j = 0; j < 8; j++) {
            int m = kb2 * 32 + q * 4 + (j & 3) + ((j >> 2) << 4);
            atomicAdd(&Lraw[b * NN + m], sum[j]);
        }
    }
}

// ---------- big path Phase 3: partial[ms] = P-slice @ G' (NO atomics) -----------
// ms=4 split, nt=1/wave, grid 1024 (4 blocks/CU). Staggered kb2 + P prefetch.
// Partials stored bf16 in the dead theta/phi workspace region.
__global__ __launch_bounds__(256, 4) void pv_kernel(
    const u16b* __restrict__ P, const u16b* __restrict__ gB, u16b* __restrict__ pvPart)
{
    int xcd = blockIdx.x & 7;                  // grid 1024
    int inner = blockIdx.x >> 3;               // 0..127
    int combo = xcd * 2 + (inner & 1);         // 0..15 = b*4+ms (XCD-pinned)
    int b = combo >> 2;
    int ms = combo & 3;                        // 4-way m-split
    int ng = inner >> 1;                       // 0..63
    int w = threadIdx.x >> 6;
    int lane = threadIdx.x & 63;
    int l15 = lane & 15, q = lane >> 4;
    int ntile = ng * 4 + w;                    // 0..255, one ntile per wave

    const u16b* Pb = P + (size_t)b * NN * NN;
    const u16b* gp = gB + (size_t)b * (NN * HIDD);

    f4v acc[8];
#pragma unroll
    for (int i = 0; i < 8; i++) acc[i] = (f4v){0.f, 0.f, 0.f, 0.f};

    int ph = ng & 31;                          // stagger phase
    int kb2_0 = ms * 32 + ph;
    s8v pcur = *reinterpret_cast<const s8v*>(Pb + ((size_t)(kb2_0 * 256 + ntile) * 64 + lane) * 8);

    for (int it = 0; it < 32; it++) {
        int kb2  = ms * 32 + ((it + ph) & 31);
        int kb2n = ms * 32 + ((it + 1 + ph) & 31);
        // prefetch next P fragment (wraps harmlessly on last iter)
        s8v pnxt = *reinterpret_cast<const s8v*>(Pb + ((size_t)(kb2n * 256 + ntile) * 64 + lane) * 8);
#pragma unroll
        for (int ot = 0; ot < 8; ot++) {
            s8v gf = *reinterpret_cast<const s8v*>(gp + ((kb2 * 8 + ot) * 64 + lane) * 8);
            acc[ot] = __builtin_amdgcn_mfma_f32_16x16x32_bf16(pcur, gf, acc[ot], 0, 0, 0);
        }
        pcur = pnxt;
    }

    u16b* pp = pvPart + (size_t)ms * ((size_t)BB * NN * HIDD) + (size_t)b * (NN * HIDD);
    int n_base = ntile * 16;
#pragma unroll
    for (int ot = 0; ot < 8; ot++) {
#pragma unroll
        for (int r = 0; r < 4; r++) {
            int n = n_base + q * 4 + r;
            int o = ot * 16 + l15;
            pp[swz(o, n, NN / 16)] = f2b(acc[ot][r]);
        }
    }
}

// ---------- big path Phase 3b: outAcc = sum of 4 bf16 partials ------------------
__global__ __launch_bounds__(256) void reduce_kernel(
    const u16b* __restrict__ pvPart, float* __restrict__ outAcc)
{
    int t = blockIdx.x * 256 + threadIdx.x;    // grid 1024 -> 262144 threads x 8
    size_t i0 = (size_t)t * 8;
    const size_t stride = (size_t)BB * NN * HIDD;
    float s[8];
#pragma unroll
    for (int j = 0; j < 8; j++) s[j] = 0.f;
#pragma unroll
    for (int p = 0; p < 4; p++) {
        s8v v = *reinterpret_cast<const s8v*>(pvPart + p * stride + i0);
#pragma unroll
        for (int j = 0; j < 8; j++) s[j] += b2f((unsigned short)v[j]);
    }
    f4v o0 = (f4v){s[0], s[1], s[2], s[3]};
    f4v o1 = (f4v){s[4], s[5], s[6], s[7]};
    *reinterpret_cast<f4v*>(outAcc + i0) = o0;
    *reinterpret_cast<f4v*>(outAcc + i0 + 4) = o1;
}

// ---------- Phase 4: y = x + w_mask @ Out^T (split path: mask is ~450-scale) ----
__global__ __launch_bounds__(256) void final_kernel(
    const float* __restrict__ x, const u16b* __restrict__ wmH, const u16b* __restrict__ wmL,
    const float* __restrict__ outAcc, float* __restrict__ y)
{
    int wave = blockIdx.x * 4 + (threadIdx.x >> 6);   // 4096 waves
    int lane = threadIdx.x & 63;
    int l15 = lane & 15, q = lane >> 4;
    int b = wave >> 10;
    int rem = wave & 1023;
    int ctile = rem >> 6;
    int n64 = rem & 63;
    const float* oa = outAcc + (size_t)b * (NN * HIDD);
    const float* xb = x + (size_t)b * CC * NN;
    float* yb = y + (size_t)b * CC * NN;
    int c0 = ctile * 16;

    s8v aH[4], aL[4];
#pragma unroll
    for (int kb = 0; kb < 4; kb++) {
        int off = (c0 + l15) * HIDD + kb * 32 + q * 8;
        aH[kb] = *reinterpret_cast<const s8v*>(wmH + off);
        aL[kb] = *reinterpret_cast<const s8v*>(wmL + off);
    }

#pragma unroll
    for (int nt = 0; nt < 4; nt++) {
        int ntile = n64 * 4 + nt;
        f4v acc = (f4v){0.f, 0.f, 0.f, 0.f};
#pragma unroll
        for (int kb = 0; kb < 4; kb++) {
            const float* bp = oa + ((size_t)(kb * 256 + ntile) * 64 + lane) * 8;
            f4v b0 = *reinterpret_cast<const f4v*>(bp);
            f4v b1 = *reinterpret_cast<const f4v*>(bp + 4);
            s8v bhv, blv;
#pragma unroll
            for (int j = 0; j < 4; j++) {
                short h, l;
                split2(b0[j], h, l); bhv[j] = h; blv[j] = l;
                split2(b1[j], h, l); bhv[j + 4] = h; blv[j + 4] = l;
            }
            acc = __builtin_amdgcn_mfma_f32_16x16x32_bf16(aH[kb], bhv, acc, 0, 0, 0);
            acc = __builtin_amdgcn_mfma_f32_16x16x32_bf16(aH[kb], blv, acc, 0, 0, 0);
            acc = __builtin_amdgcn_mfma_f32_16x16x32_bf16(aL[kb], bhv, acc, 0, 0, 0);
        }
#pragma unroll
        for (int r = 0; r < 4; r++) {
            int c = c0 + q * 4 + r;
            int n = ntile * 16 + l15;
            size_t idx = (size_t)c * NN + n;
            yb[idx] = xb[idx] + acc[r];
        }
    }
}

extern "C" void kernel_launch(void* const* d_in, const int* in_sizes, int n_in,
                              void* d_out, int out_size, void* d_ws, size_t ws_size,
                              hipStream_t stream)
{
    (void)in_sizes; (void)n_in; (void)out_size;
    const float* x  = (const float*)d_in[0];
    const float* wt = (const float*)d_in[1];
    const float* wp = (const float*)d_in[2];
    const float* wg = (const float*)d_in[3];
    const float* wm = (const float*)d_in[4];
    float* y = (float*)d_out;

    char* ws = (char*)d_ws;
    const size_t MB = 1 << 20;
    u16b* thetaH = (u16b*)(ws + 0 * MB);
    u16b* thetaL = (u16b*)(ws + 4 * MB);
    u16b* phiH   = (u16b*)(ws + 8 * MB);
    u16b* phiL   = (u16b*)(ws + 12 * MB);
    u16b* pvPart = (u16b*)(ws + 0 * MB);                   // 16 MB, overlays theta/phi
    u16b* gB     = (u16b*)(ws + 16 * MB);
    float* outAcc = (float*)(ws + 20 * MB);                // 8 MB fp32
    float* Lraw   = (float*)(ws + 28 * MB);                // 64 KB
    char* wbase = ws + 28 * MB + (64 << 10);
    u16b* wHb = (u16b*)(wbase);                            // 128 KB
    u16b* wLb = (u16b*)(wbase + (128 << 10));              // 128 KB
    u16b* wgB = (u16b*)(wbase + (256 << 10));              // 64 KB
    u16b* wmH = (u16b*)(wbase + (320 << 10));              // 64 KB
    u16b* wmL = (u16b*)(wbase + (384 << 10));              // 64 KB
    u16b* P   = (u16b*)(ws + 32 * MB);                     // 134.2 MB (big path)

    const size_t need_big = 32 * MB + (size_t)BB * NN * NN * sizeof(u16b);
    const bool big = ws_size >= need_big;

    hipMemsetAsync(outAcc, 0, (size_t)BB * NN * HIDD * sizeof(float), stream);
    hipMemsetAsync(Lraw, 0, (size_t)BB * NN * sizeof(float), stream);

    hipLaunchKernelGGL(prep_kernel, dim3(128), dim3(256), 0, stream,
                       wt, wp, wg, wm, wHb, wLb, wgB, wmH, wmL);
    hipLaunchKernelGGL(proj_kernel, dim3(512), dim3(256), 0, stream,
                       x, wHb, wLb, wgB, thetaH, thetaL, phiH, phiL, gB);

    if (big) {
        hipLaunchKernelGGL(spass_kernel,   dim3(2048), dim3(256), 0, stream,
                           thetaH, thetaL, phiH, phiL, P);
        hipLaunchKernelGGL(lreduce_kernel, dim3(512),  dim3(256), 0, stream, P, Lraw);
        hipLaunchKernelGGL(rescale_kernel, dim3(1024), dim3(256), 0, stream, gB, Lraw);
        // pv overwrites the theta/phi region (dead after spass) with bf16 partials
        hipLaunchKernelGGL(pv_kernel,      dim3(1024), dim3(256), 0, stream, P, gB, pvPart);
        hipLaunchKernelGGL(reduce_kernel,  dim3(1024), dim3(256), 0, stream, pvPart, outAcc);
    } else {
        hipLaunchKernelGGL(stats_kernel,   dim3(1024), dim3(256), 0, stream,
                           thetaH, thetaL, phiH, phiL, Lraw);
        hipLaunchKernelGGL(rescale_kernel, dim3(1024), dim3(256), 0, stream, gB, Lraw);
        hipLaunchKernelGGL(attn_kernel,    dim3(1024), dim3(256), 0, stream,
                           thetaH, thetaL, phiH, phiL, gB, outAcc);
    }
    hipLaunchKernelGGL(final_kernel, dim3(1024), dim3(256), 0, stream,
                       x, wmH, wmL, outAcc, y);
}

// Round 7
// 251.519 us; speedup vs baseline: 1.4828x; 1.0311x over previous
//
#include <hip/hip_runtime.h>

#define BB 4
#define CC 256
#define HIDD 128
#define NN 4096

typedef short s8v __attribute__((ext_vector_type(8)));
typedef float f4v __attribute__((ext_vector_type(4)));
typedef unsigned short u16b;

static __device__ __forceinline__ float b2f(unsigned short u) {
    union { unsigned int i; float f; } v; v.i = ((unsigned int)u) << 16; return v.f;
}
static __device__ __forceinline__ unsigned short f2b(float f) {
    union { float f; unsigned int i; } v; v.f = f;
    unsigned int i = v.i;
    return (unsigned short)((i + 0x7fffu + ((i >> 16) & 1u)) >> 16);
}
// fp32 -> bf16 hi + bf16 lo (combined rel err ~2^-18)
static __device__ __forceinline__ void split2(float v, short& hi, short& lo) {
    unsigned short h = f2b(v);
    hi = (short)h;
    lo = (short)f2b(v - b2f(h));
}

// Standard swizzled fragment layout for 16x16x32 MFMA operands.
// Matrix logically [K x RC]; lane l of tile (kb,cb) holds j=0..7 at
// k = kb*32+(l>>4)*8+j, rc = cb*16+(l&15) -> one contiguous 16B run per lane.
__device__ __forceinline__ int swz(int k, int rc, int CB) {
    return (((k >> 5) * CB + (rc >> 4)) * 64 + ((k >> 3) & 3) * 16 + (rc & 15)) * 8 + (k & 7);
}
// Permuted swizzle for G': k-slot (q,j) <-> m_local = (j>>2)*16 + q*4 + (j&3).
// Matches the S^T C/D layout so the P A-fragment needs NO cross-lane transform.
__device__ __forceinline__ int gswz(int m, int o) {
    int kb = m >> 5, mm = m & 31;
    int qs = (mm >> 2) & 3;
    int js = ((mm >> 4) & 1) * 4 + (mm & 3);
    return ((kb * 8 + (o >> 4)) * 64 + qs * 16 + (o & 15)) * 8 + js;
}

// ---------- Phase 0: weights -> bf16 (theta/phi/mask split hi+lo, g plain) ------
__global__ __launch_bounds__(256) void prep_kernel(
    const float* __restrict__ wt, const float* __restrict__ wp,
    const float* __restrict__ wg, const float* __restrict__ wm,
    u16b* __restrict__ wHb, u16b* __restrict__ wLb, u16b* __restrict__ wgB,
    u16b* __restrict__ wmH, u16b* __restrict__ wmL)
{
    int t = blockIdx.x * 256 + threadIdx.x;   // grid 128 -> 32768 = HID*CC
    short h, l;
    split2(wt[t], h, l); wHb[t] = (u16b)h;           wLb[t] = (u16b)l;
    split2(wp[t], h, l); wHb[32768 + t] = (u16b)h;   wLb[32768 + t] = (u16b)l;
    wgB[t] = f2b(wg[t]);
    split2(wm[t], h, l); wmH[t] = (u16b)h;           wmL[t] = (u16b)l;
}

// ---------- Phase 1: Theta/Phi (split, swizzled) and G (plain, perm-swizzled) ---
// Software-pipelined x loads (next kc prefetched across the MFMA block).
__global__ __launch_bounds__(256) void proj_kernel(
    const float* __restrict__ x, const u16b* __restrict__ wHb, const u16b* __restrict__ wLb,
    const u16b* __restrict__ wgB,
    u16b* __restrict__ thetaH, u16b* __restrict__ thetaL,
    u16b* __restrict__ phiH, u16b* __restrict__ phiL, u16b* __restrict__ gB)
{
    int wave = blockIdx.x * 4 + (threadIdx.x >> 6);   // 2048 waves
    int lane = threadIdx.x & 63;
    int l15 = lane & 15, q = lane >> 4;
    int b = wave >> 9;
    int rem = wave & 511;
    int ntile = rem >> 1;
    int half = rem & 1;                                // ot range half*4..half*4+3
    int n0 = ntile << 4;
    const float* xb = x + (size_t)b * CC * NN;

    f4v acc[3][4];
#pragma unroll
    for (int m = 0; m < 3; m++)
#pragma unroll
        for (int i = 0; i < 4; i++) acc[m][i] = (f4v){0.f, 0.f, 0.f, 0.f};

    float xv[8];
    {
        const float* xp = xb + (size_t)(q * 8) * NN + n0 + l15;
#pragma unroll
        for (int j = 0; j < 8; j++) xv[j] = xp[(size_t)j * NN];
    }

    for (int kc = 0; kc < 8; kc++) {
        int c0 = kc * 32;
        float xn[8];
        if (kc < 7) {
            const float* xp = xb + (size_t)(c0 + 32 + q * 8) * NN + n0 + l15;
#pragma unroll
            for (int j = 0; j < 8; j++) xn[j] = xp[(size_t)j * NN];
        }
        s8v bh, bl;
#pragma unroll
        for (int j = 0; j < 8; j++) {
            short h, l;
            split2(xv[j], h, l);
            bh[j] = h; bl[j] = l;
        }
#pragma unroll
        for (int mat = 0; mat < 2; mat++) {
#pragma unroll
            for (int otl = 0; otl < 4; otl++) {
                int ot = half * 4 + otl;
                int woff = mat * 32768 + (ot * 16 + l15) * CC + c0 + q * 8;
                s8v ah = *reinterpret_cast<const s8v*>(wHb + woff);
                s8v al = *reinterpret_cast<const s8v*>(wLb + woff);
                acc[mat][otl] = __builtin_amdgcn_mfma_f32_16x16x32_bf16(ah, bh, acc[mat][otl], 0, 0, 0);
                acc[mat][otl] = __builtin_amdgcn_mfma_f32_16x16x32_bf16(ah, bl, acc[mat][otl], 0, 0, 0);
                acc[mat][otl] = __builtin_amdgcn_mfma_f32_16x16x32_bf16(al, bh, acc[mat][otl], 0, 0, 0);
            }
        }
#pragma unroll
        for (int otl = 0; otl < 4; otl++) {
            int ot = half * 4 + otl;
            const s8v* gw = reinterpret_cast<const s8v*>(wgB + (ot * 16 + l15) * CC + c0 + q * 8);
            acc[2][otl] = __builtin_amdgcn_mfma_f32_16x16x32_bf16(*gw, bh, acc[2][otl], 0, 0, 0);
        }
        if (kc < 7) {
#pragma unroll
            for (int j = 0; j < 8; j++) xv[j] = xn[j];
        }
    }

    size_t boff = (size_t)b * (NN * HIDD);
#pragma unroll
    for (int otl = 0; otl < 4; otl++) {
#pragma unroll
        for (int r = 0; r < 4; r++) {
            int o = (half * 4 + otl) * 16 + q * 4 + r;   // C/D row (hid)
            int n = n0 + l15;                             // C/D col (spatial)
            int offTP = swz(o, n, NN / 16);
            short h, l;
            split2(acc[0][otl][r], h, l);
            thetaH[boff + offTP] = (u16b)h; thetaL[boff + offTP] = (u16b)l;
            split2(acc[1][otl][r], h, l);
            phiH[boff + offTP] = (u16b)h;   phiL[boff + offTP] = (u16b)l;
            gB[boff + gswz(n, o)] = f2b(acc[2][otl][r]);
        }
    }
}

// ---------- small path Phase 2: Lraw[m] = sum_n e^{s[n][m]} ---------------------
__global__ __launch_bounds__(256, 2) void stats_kernel(
    const u16b* __restrict__ thetaH, const u16b* __restrict__ thetaL,
    const u16b* __restrict__ phiH, const u16b* __restrict__ phiL,
    float* __restrict__ Lraw)
{
    int xcd = blockIdx.x & 7;                  // grid 1024
    int inner = blockIdx.x >> 3;               // 0..127
    int b = xcd >> 1;
    int su = (xcd & 1) * 128 + inner;          // 0..255 within batch
    int w = threadIdx.x >> 6;
    int wu = su * 4 + w;                       // 0..1023
    int mg = wu >> 4;                          // 64 groups of 4 mtiles
    int ns = wu & 15;                          // 16-way n-split
    int lane = threadIdx.x & 63;

    size_t boff = (size_t)b * (NN * HIDD);
    const u16b* thH = thetaH + boff; const u16b* thL = thetaL + boff;
    const u16b* phH = phiH + boff;   const u16b* phL = phiL + boff;

    s8v pBh[4][4], pBl[4][4];
#pragma unroll
    for (int mt = 0; mt < 4; mt++)
#pragma unroll
        for (int kb = 0; kb < 4; kb++) {
            int off = ((kb * 256 + (mg * 4 + mt)) * 64 + lane) * 8;
            pBh[mt][kb] = *reinterpret_cast<const s8v*>(phH + off);
            pBl[mt][kb] = *reinterpret_cast<const s8v*>(phL + off);
        }

    float Lp[4];
#pragma unroll
    for (int i = 0; i < 4; i++) Lp[i] = 0.f;

    for (int i = 0; i < 16; i++) {
        int ntile = ns * 16 + i;
        s8v tAh[4], tAl[4];
#pragma unroll
        for (int kb = 0; kb < 4; kb++) {
            int off = ((kb * 256 + ntile) * 64 + lane) * 8;
            tAh[kb] = *reinterpret_cast<const s8v*>(thH + off);
            tAl[kb] = *reinterpret_cast<const s8v*>(thL + off);
        }
#pragma unroll
        for (int mt = 0; mt < 4; mt++) {
            f4v shh = (f4v){0.f, 0.f, 0.f, 0.f};
            f4v sx  = (f4v){0.f, 0.f, 0.f, 0.f};
#pragma unroll
            for (int kb = 0; kb < 4; kb++)
                shh = __builtin_amdgcn_mfma_f32_16x16x32_bf16(tAh[kb], pBh[mt][kb], shh, 0, 0, 0);
#pragma unroll
            for (int kb = 0; kb < 4; kb++) {
                sx = __builtin_amdgcn_mfma_f32_16x16x32_bf16(tAh[kb], pBl[mt][kb], sx, 0, 0, 0);
                sx = __builtin_amdgcn_mfma_f32_16x16x32_bf16(tAl[kb], pBh[mt][kb], sx, 0, 0, 0);
            }
            Lp[mt] += (__expf(shh[0] + sx[0]) + __expf(shh[1] + sx[1]))
                    + (__expf(shh[2] + sx[2]) + __expf(shh[3] + sx[3]));
        }
    }
#pragma unroll
    for (int mt = 0; mt < 4; mt++) {
        float v = Lp[mt];
        v += __shfl_xor(v, 16);
        v += __shfl_xor(v, 32);
        if (lane < 16) atomicAdd(&Lraw[b * NN + (mg * 4 + mt) * 16 + lane], v);
    }
}

// ---------- Phase 2b: G'[m,o] = G[m,o] / L[m]  (in place, perm-swizzled) --------
__global__ __launch_bounds__(256) void rescale_kernel(
    u16b* __restrict__ gB, const float* __restrict__ Lraw)
{
    int t = blockIdx.x * 256 + threadIdx.x;    // grid 1024
    int flat0 = t * 8;
    int b = flat0 >> 19;
    int rem = flat0 & ((NN * HIDD) - 1);
    int kb = rem >> 12;
    int lane = (rem >> 3) & 63;
    int qs = lane >> 4;
    int mbase = kb * 32 + qs * 4;
    const float* Lp = Lraw + b * NN + mbase;
    u16b* gp = gB + flat0;
    s8v g = *reinterpret_cast<const s8v*>(gp);
    s8v o;
#pragma unroll
    for (int j = 0; j < 8; j++) {
        float v = b2f((unsigned short)g[j]) / Lp[((j >> 2) << 4) + (j & 3)];
        o[j] = (short)f2b(v);
    }
    *reinterpret_cast<s8v*>(gp) = o;
}

// ---------- small path Phase 3: Out += softmax(S) @ G', fused S^T recompute -----
__global__ __launch_bounds__(256, 2) void attn_kernel(
    const u16b* __restrict__ thetaH, const u16b* __restrict__ thetaL,
    const u16b* __restrict__ phiH, const u16b* __restrict__ phiL,
    const u16b* __restrict__ gB, float* __restrict__ outAcc)
{
    int xcd = blockIdx.x & 7;                  // grid 1024
    int inner = blockIdx.x >> 3;               // 0..127
    int combo = xcd * 4 + (inner & 3);         // 0..31 = b*8+ms (XCD-pinned)
    int b = combo >> 3;
    int ms = combo & 7;                        // 8-way m-split
    int ng = inner >> 2;                       // 0..31
    int w = threadIdx.x >> 6;
    int lane = threadIdx.x & 63;
    int l15 = lane & 15, q = lane >> 4;
    int ntile0 = ng * 8 + w * 2;

    size_t boff = (size_t)b * (NN * HIDD);
    const u16b* thH = thetaH + boff; const u16b* thL = thetaL + boff;
    const u16b* phH = phiH + boff;   const u16b* phL = phiL + boff;
    const u16b* gp = gB + boff;

    s8v tBh[2][4], tBl[2][4];
#pragma unroll
    for (int nt = 0; nt < 2; nt++)
#pragma unroll
        for (int kb = 0; kb < 4; kb++) {
            int off = ((kb * 256 + ntile0 + nt) * 64 + lane) * 8;
            tBh[nt][kb] = *reinterpret_cast<const s8v*>(thH + off);
            tBl[nt][kb] = *reinterpret_cast<const s8v*>(thL + off);
        }

    f4v acc[2][8];
#pragma unroll
    for (int nt = 0; nt < 2; nt++)
#pragma unroll
        for (int i = 0; i < 8; i++) acc[nt][i] = (f4v){0.f, 0.f, 0.f, 0.f};

    for (int mt = 0; mt < 16; mt++) {
        int m0 = ms * 512 + mt * 32;
        s8v pf[2];
#pragma unroll
        for (int h = 0; h < 2; h++) {
            int mtile = (m0 >> 4) + h;
            s8v pAh[4], pAl[4];
#pragma unroll
            for (int kb = 0; kb < 4; kb++) {
                int off = ((kb * 256 + mtile) * 64 + lane) * 8;
                pAh[kb] = *reinterpret_cast<const s8v*>(phH + off);
                pAl[kb] = *reinterpret_cast<const s8v*>(phL + off);
            }
#pragma unroll
            for (int nt = 0; nt < 2; nt++) {
                f4v shh = (f4v){0.f, 0.f, 0.f, 0.f};
                f4v sx  = (f4v){0.f, 0.f, 0.f, 0.f};
#pragma unroll
                for (int kb = 0; kb < 4; kb++)
                    shh = __builtin_amdgcn_mfma_f32_16x16x32_bf16(pAh[kb], tBh[nt][kb], shh, 0, 0, 0);
#pragma unroll
                for (int kb = 0; kb < 4; kb++) {
                    sx = __builtin_amdgcn_mfma_f32_16x16x32_bf16(pAh[kb], tBl[nt][kb], sx, 0, 0, 0);
                    sx = __builtin_amdgcn_mfma_f32_16x16x32_bf16(pAl[kb], tBh[nt][kb], sx, 0, 0, 0);
                }
#pragma unroll
                for (int r = 0; r < 4; r++)
                    pf[nt][h * 4 + r] = (short)f2b(__expf(shh[r] + sx[r]));
            }
        }
        int kb2 = m0 >> 5;
#pragma unroll
        for (int ot = 0; ot < 8; ot++) {
            s8v gf = *reinterpret_cast<const s8v*>(gp + ((kb2 * 8 + ot) * 64 + lane) * 8);
#pragma unroll
            for (int nt = 0; nt < 2; nt++)
                acc[nt][ot] = __builtin_amdgcn_mfma_f32_16x16x32_bf16(pf[nt], gf, acc[nt][ot], 0, 0, 0);
        }
    }

    float* oa = outAcc + (size_t)b * (NN * HIDD);
#pragma unroll
    for (int nt = 0; nt < 2; nt++) {
        int n_base = (ntile0 + nt) * 16;
#pragma unroll
        for (int ot = 0; ot < 8; ot++) {
#pragma unroll
            for (int r = 0; r < 4; r++) {
                int n = n_base + q * 4 + r;
                int o = ot * 16 + l15;
                atomicAdd(&oa[swz(o, n, NN / 16)], acc[nt][ot][r]);
            }
        }
    }
}

// ---------- big path Phase 2: S-pass -> P = e^s (A-frag layout) + fused L sum ---
__global__ __launch_bounds__(256, 2) void spass_kernel(
    const u16b* __restrict__ thetaH, const u16b* __restrict__ thetaL,
    const u16b* __restrict__ phiH, const u16b* __restrict__ phiL,
    u16b* __restrict__ P, float* __restrict__ Lraw)
{
    int xcd = blockIdx.x & 7;                  // grid 2048
    int inner = blockIdx.x >> 3;               // 0..255
    int combo = xcd * 8 + (inner & 7);         // 0..63 = b*16+ms
    int b = combo >> 4;
    int ms = combo & 15;                       // 16-way m-split
    int ng = inner >> 3;                       // 0..31
    int w = threadIdx.x >> 6;
    int lane = threadIdx.x & 63;
    int l15 = lane & 15, q = lane >> 4;
    int ntile0 = ng * 8 + w * 2;

    size_t boff = (size_t)b * (NN * HIDD);
    const u16b* thH = thetaH + boff; const u16b* thL = thetaL + boff;
    const u16b* phH = phiH + boff;   const u16b* phL = phiL + boff;
    u16b* Pb = P + (size_t)b * NN * NN;
    float* Lb = Lraw + b * NN;

    s8v tBh[2][4], tBl[2][4];
#pragma unroll
    for (int nt = 0; nt < 2; nt++)
#pragma unroll
        for (int kb = 0; kb < 4; kb++) {
            int off = ((kb * 256 + ntile0 + nt) * 64 + lane) * 8;
            tBh[nt][kb] = *reinterpret_cast<const s8v*>(thH + off);
            tBl[nt][kb] = *reinterpret_cast<const s8v*>(thL + off);
        }

    int ph = ng & 7;                           // stagger phase
    for (int mt = 0; mt < 8; mt++) {
        int mtr = (mt + ph) & 7;
        int m0 = ms * 256 + mtr * 32;
        float ev[2][2][4];
#pragma unroll
        for (int h = 0; h < 2; h++) {
            int mtile = (m0 >> 4) + h;
            s8v pAh[4], pAl[4];
#pragma unroll
            for (int kb = 0; kb < 4; kb++) {
                int off = ((kb * 256 + mtile) * 64 + lane) * 8;
                pAh[kb] = *reinterpret_cast<const s8v*>(phH + off);
                pAl[kb] = *reinterpret_cast<const s8v*>(phL + off);
            }
#pragma unroll
            for (int nt = 0; nt < 2; nt++) {
                f4v shh = (f4v){0.f, 0.f, 0.f, 0.f};
                f4v sx  = (f4v){0.f, 0.f, 0.f, 0.f};
#pragma unroll
                for (int kb = 0; kb < 4; kb++)
                    shh = __builtin_amdgcn_mfma_f32_16x16x32_bf16(pAh[kb], tBh[nt][kb], shh, 0, 0, 0);
#pragma unroll
                for (int kb = 0; kb < 4; kb++) {
                    sx = __builtin_amdgcn_mfma_f32_16x16x32_bf16(pAh[kb], tBl[nt][kb], sx, 0, 0, 0);
                    sx = __builtin_amdgcn_mfma_f32_16x16x32_bf16(pAl[kb], tBh[nt][kb], sx, 0, 0, 0);
                }
#pragma unroll
                for (int r = 0; r < 4; r++)
                    ev[nt][h][r] = __expf(shh[r] + sx[r]);
            }
        }
        // store P fragments
        int kb2 = m0 >> 5;
#pragma unroll
        for (int nt = 0; nt < 2; nt++) {
            s8v pf;
#pragma unroll
            for (int j = 0; j < 8; j++) pf[j] = (short)f2b(ev[nt][j >> 2][j & 3]);
            *reinterpret_cast<s8v*>(Pb + ((size_t)(kb2 * 256 + ntile0 + nt) * 64 + lane) * 8) = pf;
        }
        // fused column-sum: reduce over the 32 n this wave owns (both nt + l15 lanes)
        float cs[8];
#pragma unroll
        for (int j = 0; j < 8; j++) {
            cs[j] = ev[0][j >> 2][j & 3] + ev[1][j >> 2][j & 3];
            cs[j] += __shfl_xor(cs[j], 1);
            cs[j] += __shfl_xor(cs[j], 2);
            cs[j] += __shfl_xor(cs[j], 4);
            cs[j] += __shfl_xor(cs[j], 8);
        }
        if (l15 == 0) {
#pragma unroll
            for (int j = 0; j < 8; j++) {
                int m = m0 + (j >> 2) * 16 + q * 4 + (j & 3);
                atomicAdd(&Lb[m], cs[j]);
            }
        }
    }
}

// ---------- big path Phase 3: partial[ms] = P-slice @ G' (NO atomics) -----------
__global__ __launch_bounds__(256, 4) void pv_kernel(
    const u16b* __restrict__ P, const u16b* __restrict__ gB, u16b* __restrict__ pvPart)
{
    int xcd = blockIdx.x & 7;                  // grid 1024
    int inner = blockIdx.x >> 3;               // 0..127
    int combo = xcd * 2 + (inner & 1);         // 0..15 = b*4+ms (XCD-pinned)
    int b = combo >> 2;
    int ms = combo & 3;                        // 4-way m-split
    int ng = inner >> 1;                       // 0..63
    int w = threadIdx.x >> 6;
    int lane = threadIdx.x & 63;
    int l15 = lane & 15, q = lane >> 4;
    int ntile = ng * 4 + w;                    // 0..255, one ntile per wave

    const u16b* Pb = P + (size_t)b * NN * NN;
    const u16b* gp = gB + (size_t)b * (NN * HIDD);

    f4v acc[8];
#pragma unroll
    for (int i = 0; i < 8; i++) acc[i] = (f4v){0.f, 0.f, 0.f, 0.f};

    int ph = ng & 31;                          // stagger phase
    int kb2_0 = ms * 32 + ph;
    s8v pcur = *reinterpret_cast<const s8v*>(Pb + ((size_t)(kb2_0 * 256 + ntile) * 64 + lane) * 8);

    for (int it = 0; it < 32; it++) {
        int kb2  = ms * 32 + ((it + ph) & 31);
        int kb2n = ms * 32 + ((it + 1 + ph) & 31);
        s8v pnxt = *reinterpret_cast<const s8v*>(Pb + ((size_t)(kb2n * 256 + ntile) * 64 + lane) * 8);
#pragma unroll
        for (int ot = 0; ot < 8; ot++) {
            s8v gf = *reinterpret_cast<const s8v*>(gp + ((kb2 * 8 + ot) * 64 + lane) * 8);
            acc[ot] = __builtin_amdgcn_mfma_f32_16x16x32_bf16(pcur, gf, acc[ot], 0, 0, 0);
        }
        pcur = pnxt;
    }

    u16b* pp = pvPart + (size_t)ms * ((size_t)BB * NN * HIDD) + (size_t)b * (NN * HIDD);
    int n_base = ntile * 16;
#pragma unroll
    for (int ot = 0; ot < 8; ot++) {
#pragma unroll
        for (int r = 0; r < 4; r++) {
            int n = n_base + q * 4 + r;
            int o = ot * 16 + l15;
            pp[swz(o, n, NN / 16)] = f2b(acc[ot][r]);
        }
    }
}

// ---------- big path Phase 4: y = x + w_mask @ (sum of partials)^T --------------
__global__ __launch_bounds__(256) void final_big_kernel(
    const float* __restrict__ x, const u16b* __restrict__ wmH, const u16b* __restrict__ wmL,
    const u16b* __restrict__ pvPart, float* __restrict__ y)
{
    int wave = blockIdx.x * 4 + (threadIdx.x >> 6);   // 4096 waves
    int lane = threadIdx.x & 63;
    int l15 = lane & 15, q = lane >> 4;
    int b = wave >> 10;
    int rem = wave & 1023;
    int ctile = rem >> 6;
    int n64 = rem & 63;
    const size_t pstride = (size_t)BB * NN * HIDD;
    const u16b* pb = pvPart + (size_t)b * (NN * HIDD);
    const float* xb = x + (size_t)b * CC * NN;
    float* yb = y + (size_t)b * CC * NN;
    int c0 = ctile * 16;

    s8v aH[4], aL[4];
#pragma unroll
    for (int kb = 0; kb < 4; kb++) {
        int off = (c0 + l15) * HIDD + kb * 32 + q * 8;
        aH[kb] = *reinterpret_cast<const s8v*>(wmH + off);
        aL[kb] = *reinterpret_cast<const s8v*>(wmL + off);
    }

#pragma unroll
    for (int nt = 0; nt < 4; nt++) {
        int ntile = n64 * 4 + nt;
        f4v acc = (f4v){0.f, 0.f, 0.f, 0.f};
#pragma unroll
        for (int kb = 0; kb < 4; kb++) {
            size_t fo = ((size_t)(kb * 256 + ntile) * 64 + lane) * 8;
            float s[8];
#pragma unroll
            for (int j = 0; j < 8; j++) s[j] = 0.f;
#pragma unroll
            for (int p = 0; p < 4; p++) {
                s8v v = *reinterpret_cast<const s8v*>(pb + p * pstride + fo);
#pragma unroll
                for (int j = 0; j < 8; j++) s[j] += b2f((unsigned short)v[j]);
            }
            s8v bhv, blv;
#pragma unroll
            for (int j = 0; j < 8; j++) {
                short h, l;
                split2(s[j], h, l);
                bhv[j] = h; blv[j] = l;
            }
            acc = __builtin_amdgcn_mfma_f32_16x16x32_bf16(aH[kb], bhv, acc, 0, 0, 0);
            acc = __builtin_amdgcn_mfma_f32_16x16x32_bf16(aH[kb], blv, acc, 0, 0, 0);
            acc = __builtin_amdgcn_mfma_f32_16x16x32_bf16(aL[kb], bhv, acc, 0, 0, 0);
        }
#pragma unroll
        for (int r = 0; r < 4; r++) {
            int c = c0 + q * 4 + r;
            int n = ntile * 16 + l15;
            size_t idx = (size_t)c * NN + n;
            yb[idx] = xb[idx] + acc[r];
        }
    }
}

// ---------- small path Phase 4: y = x + w_mask @ Out^T --------------------------
__global__ __launch_bounds__(256) void final_kernel(
    const float* __restrict__ x, const u16b* __restrict__ wmH, const u16b* __restrict__ wmL,
    const float* __restrict__ outAcc, float* __restrict__ y)
{
    int wave = blockIdx.x * 4 + (threadIdx.x >> 6);   // 4096 waves
    int lane = threadIdx.x & 63;
    int l15 = lane & 15, q = lane >> 4;
    int b = wave >> 10;
    int rem = wave & 1023;
    int ctile = rem >> 6;
    int n64 = rem & 63;
    const float* oa = outAcc + (size_t)b * (NN * HIDD);
    const float* xb = x + (size_t)b * CC * NN;
    float* yb = y + (size_t)b * CC * NN;
    int c0 = ctile * 16;

    s8v aH[4], aL[4];
#pragma unroll
    for (int kb = 0; kb < 4; kb++) {
        int off = (c0 + l15) * HIDD + kb * 32 + q * 8;
        aH[kb] = *reinterpret_cast<const s8v*>(wmH + off);
        aL[kb] = *reinterpret_cast<const s8v*>(wmL + off);
    }

#pragma unroll
    for (int nt = 0; nt < 4; nt++) {
        int ntile = n64 * 4 + nt;
        f4v acc = (f4v){0.f, 0.f, 0.f, 0.f};
#pragma unroll
        for (int kb = 0; kb < 4; kb++) {
            const float* bp = oa + ((size_t)(kb * 256 + ntile) * 64 + lane) * 8;
            f4v b0 = *reinterpret_cast<const f4v*>(bp);
            f4v b1 = *reinterpret_cast<const f4v*>(bp + 4);
            s8v bhv, blv;
#pragma unroll
            for (int j = 0; j < 4; j++) {
                short h, l;
                split2(b0[j], h, l); bhv[j] = h; blv[j] = l;
                split2(b1[j], h, l); bhv[j + 4] = h; blv[j + 4] = l;
            }
            acc = __builtin_amdgcn_mfma_f32_16x16x32_bf16(aH[kb], bhv, acc, 0, 0, 0);
            acc = __builtin_amdgcn_mfma_f32_16x16x32_bf16(aH[kb], blv, acc, 0, 0, 0);
            acc = __builtin_amdgcn_mfma_f32_16x16x32_bf16(aL[kb], bhv, acc, 0, 0, 0);
        }
#pragma unroll
        for (int r = 0; r < 4; r++) {
            int c = c0 + q * 4 + r;
            int n = ntile * 16 + l15;
            size_t idx = (size_t)c * NN + n;
            yb[idx] = xb[idx] + acc[r];
        }
    }
}

extern "C" void kernel_launch(void* const* d_in, const int* in_sizes, int n_in,
                              void* d_out, int out_size, void* d_ws, size_t ws_size,
                              hipStream_t stream)
{
    (void)in_sizes; (void)n_in; (void)out_size;
    const float* x  = (const float*)d_in[0];
    const float* wt = (const float*)d_in[1];
    const float* wp = (const float*)d_in[2];
    const float* wg = (const float*)d_in[3];
    const float* wm = (const float*)d_in[4];
    float* y = (float*)d_out;

    char* ws = (char*)d_ws;
    const size_t MB = 1 << 20;
    u16b* thetaH = (u16b*)(ws + 0 * MB);
    u16b* thetaL = (u16b*)(ws + 4 * MB);
    u16b* phiH   = (u16b*)(ws + 8 * MB);
    u16b* phiL   = (u16b*)(ws + 12 * MB);
    u16b* pvPart = (u16b*)(ws + 0 * MB);                   // 16 MB, overlays theta/phi
    u16b* gB     = (u16b*)(ws + 16 * MB);
    float* outAcc = (float*)(ws + 20 * MB);                // 8 MB fp32 (small path)
    float* Lraw   = (float*)(ws + 28 * MB);                // 64 KB
    char* wbase = ws + 28 * MB + (64 << 10);
    u16b* wHb = (u16b*)(wbase);                            // 128 KB
    u16b* wLb = (u16b*)(wbase + (128 << 10));              // 128 KB
    u16b* wgB = (u16b*)(wbase + (256 << 10));              // 64 KB
    u16b* wmH = (u16b*)(wbase + (320 << 10));              // 64 KB
    u16b* wmL = (u16b*)(wbase + (384 << 10));              // 64 KB
    u16b* P   = (u16b*)(ws + 32 * MB);                     // 134.2 MB (big path)

    const size_t need_big = 32 * MB + (size_t)BB * NN * NN * sizeof(u16b);
    const bool big = ws_size >= need_big;

    hipMemsetAsync(Lraw, 0, (size_t)BB * NN * sizeof(float), stream);

    hipLaunchKernelGGL(prep_kernel, dim3(128), dim3(256), 0, stream,
                       wt, wp, wg, wm, wHb, wLb, wgB, wmH, wmL);
    hipLaunchKernelGGL(proj_kernel, dim3(512), dim3(256), 0, stream,
                       x, wHb, wLb, wgB, thetaH, thetaL, phiH, phiL, gB);

    if (big) {
        hipLaunchKernelGGL(spass_kernel,   dim3(2048), dim3(256), 0, stream,
                           thetaH, thetaL, phiH, phiL, P, Lraw);
        hipLaunchKernelGGL(rescale_kernel, dim3(1024), dim3(256), 0, stream, gB, Lraw);
        // pv overwrites the theta/phi region (dead after spass) with bf16 partials
        hipLaunchKernelGGL(pv_kernel,      dim3(1024), dim3(256), 0, stream, P, gB, pvPart);
        hipLaunchKernelGGL(final_big_kernel, dim3(1024), dim3(256), 0, stream,
                           x, wmH, wmL, pvPart, y);
    } else {
        hipMemsetAsync(outAcc, 0, (size_t)BB * NN * HIDD * sizeof(float), stream);
        hipLaunchKernelGGL(stats_kernel,   dim3(1024), dim3(256), 0, stream,
                           thetaH, thetaL, phiH, phiL, Lraw);
        hipLaunchKernelGGL(rescale_kernel, dim3(1024), dim3(256), 0, stream, gB, Lraw);
        hipLaunchKernelGGL(attn_kernel,    dim3(1024), dim3(256), 0, stream,
                           thetaH, thetaL, phiH, phiL, gB, outAcc);
        hipLaunchKernelGGL(final_kernel,   dim3(1024), dim3(256), 0, stream,
                           x, wmH, wmL, outAcc, y);
    }
}

// Round 8
// 245.051 us; speedup vs baseline: 1.5220x; 1.0264x over previous
//
#include <hip/hip_runtime.h>

#define BB 4
#define CC 256
#define HIDD 128
#define NN 4096

typedef short s8v __attribute__((ext_vector_type(8)));
typedef float f4v __attribute__((ext_vector_type(4)));
typedef unsigned short u16b;

static __device__ __forceinline__ float b2f(unsigned short u) {
    union { unsigned int i; float f; } v; v.i = ((unsigned int)u) << 16; return v.f;
}
static __device__ __forceinline__ unsigned short f2b(float f) {
    union { float f; unsigned int i; } v; v.f = f;
    unsigned int i = v.i;
    return (unsigned short)((i + 0x7fffu + ((i >> 16) & 1u)) >> 16);
}
// fp32 -> bf16 hi + bf16 lo (combined rel err ~2^-18)
static __device__ __forceinline__ void split2(float v, short& hi, short& lo) {
    unsigned short h = f2b(v);
    hi = (short)h;
    lo = (short)f2b(v - b2f(h));
}

// Standard swizzled fragment layout for 16x16x32 MFMA operands.
__device__ __forceinline__ int swz(int k, int rc, int CB) {
    return (((k >> 5) * CB + (rc >> 4)) * 64 + ((k >> 3) & 3) * 16 + (rc & 15)) * 8 + (k & 7);
}
// Permuted swizzle for G': k-slot (q,j) <-> m_local = (j>>2)*16 + q*4 + (j&3).
__device__ __forceinline__ int gswz(int m, int o) {
    int kb = m >> 5, mm = m & 31;
    int qs = (mm >> 2) & 3;
    int js = ((mm >> 4) & 1) * 4 + (mm & 3);
    return ((kb * 8 + (o >> 4)) * 64 + qs * 16 + (o & 15)) * 8 + js;
}

// ---------- Phase 0: weights -> bf16 (theta/phi/mask split hi+lo, g plain) ------
__global__ __launch_bounds__(256) void prep_kernel(
    const float* __restrict__ wt, const float* __restrict__ wp,
    const float* __restrict__ wg, const float* __restrict__ wm,
    u16b* __restrict__ wHb, u16b* __restrict__ wLb, u16b* __restrict__ wgB,
    u16b* __restrict__ wmH, u16b* __restrict__ wmL)
{
    int t = blockIdx.x * 256 + threadIdx.x;   // grid 128 -> 32768 = HID*CC
    short h, l;
    split2(wt[t], h, l); wHb[t] = (u16b)h;           wLb[t] = (u16b)l;
    split2(wp[t], h, l); wHb[32768 + t] = (u16b)h;   wLb[32768 + t] = (u16b)l;
    wgB[t] = f2b(wg[t]);
    split2(wm[t], h, l); wmH[t] = (u16b)h;           wmL[t] = (u16b)l;
}

// ---------- Phase 1: Theta/Phi (split, swizzled) and G (plain, perm-swizzled) ---
__global__ __launch_bounds__(256) void proj_kernel(
    const float* __restrict__ x, const u16b* __restrict__ wHb, const u16b* __restrict__ wLb,
    const u16b* __restrict__ wgB,
    u16b* __restrict__ thetaH, u16b* __restrict__ thetaL,
    u16b* __restrict__ phiH, u16b* __restrict__ phiL, u16b* __restrict__ gB)
{
    int wave = blockIdx.x * 4 + (threadIdx.x >> 6);   // 2048 waves
    int lane = threadIdx.x & 63;
    int l15 = lane & 15, q = lane >> 4;
    int b = wave >> 9;
    int rem = wave & 511;
    int ntile = rem >> 1;
    int half = rem & 1;                                // ot range half*4..half*4+3
    int n0 = ntile << 4;
    const float* xb = x + (size_t)b * CC * NN;

    f4v acc[3][4];
#pragma unroll
    for (int m = 0; m < 3; m++)
#pragma unroll
        for (int i = 0; i < 4; i++) acc[m][i] = (f4v){0.f, 0.f, 0.f, 0.f};

    float xv[8];
    {
        const float* xp = xb + (size_t)(q * 8) * NN + n0 + l15;
#pragma unroll
        for (int j = 0; j < 8; j++) xv[j] = xp[(size_t)j * NN];
    }

    for (int kc = 0; kc < 8; kc++) {
        int c0 = kc * 32;
        float xn[8];
        if (kc < 7) {
            const float* xp = xb + (size_t)(c0 + 32 + q * 8) * NN + n0 + l15;
#pragma unroll
            for (int j = 0; j < 8; j++) xn[j] = xp[(size_t)j * NN];
        }
        s8v bh, bl;
#pragma unroll
        for (int j = 0; j < 8; j++) {
            short h, l;
            split2(xv[j], h, l);
            bh[j] = h; bl[j] = l;
        }
#pragma unroll
        for (int mat = 0; mat < 2; mat++) {
#pragma unroll
            for (int otl = 0; otl < 4; otl++) {
                int ot = half * 4 + otl;
                int woff = mat * 32768 + (ot * 16 + l15) * CC + c0 + q * 8;
                s8v ah = *reinterpret_cast<const s8v*>(wHb + woff);
                s8v al = *reinterpret_cast<const s8v*>(wLb + woff);
                acc[mat][otl] = __builtin_amdgcn_mfma_f32_16x16x32_bf16(ah, bh, acc[mat][otl], 0, 0, 0);
                acc[mat][otl] = __builtin_amdgcn_mfma_f32_16x16x32_bf16(ah, bl, acc[mat][otl], 0, 0, 0);
                acc[mat][otl] = __builtin_amdgcn_mfma_f32_16x16x32_bf16(al, bh, acc[mat][otl], 0, 0, 0);
            }
        }
#pragma unroll
        for (int otl = 0; otl < 4; otl++) {
            int ot = half * 4 + otl;
            const s8v* gw = reinterpret_cast<const s8v*>(wgB + (ot * 16 + l15) * CC + c0 + q * 8);
            acc[2][otl] = __builtin_amdgcn_mfma_f32_16x16x32_bf16(*gw, bh, acc[2][otl], 0, 0, 0);
        }
        if (kc < 7) {
#pragma unroll
            for (int j = 0; j < 8; j++) xv[j] = xn[j];
        }
    }

    size_t boff = (size_t)b * (NN * HIDD);
#pragma unroll
    for (int otl = 0; otl < 4; otl++) {
#pragma unroll
        for (int r = 0; r < 4; r++) {
            int o = (half * 4 + otl) * 16 + q * 4 + r;   // C/D row (hid)
            int n = n0 + l15;                             // C/D col (spatial)
            int offTP = swz(o, n, NN / 16);
            short h, l;
            split2(acc[0][otl][r], h, l);
            thetaH[boff + offTP] = (u16b)h; thetaL[boff + offTP] = (u16b)l;
            split2(acc[1][otl][r], h, l);
            phiH[boff + offTP] = (u16b)h;   phiL[boff + offTP] = (u16b)l;
            gB[boff + gswz(n, o)] = f2b(acc[2][otl][r]);
        }
    }
}

// ---------- small path Phase 2: Lraw[m] = sum_n e^{s[n][m]} ---------------------
__global__ __launch_bounds__(256, 2) void stats_kernel(
    const u16b* __restrict__ thetaH, const u16b* __restrict__ thetaL,
    const u16b* __restrict__ phiH, const u16b* __restrict__ phiL,
    float* __restrict__ Lraw)
{
    int xcd = blockIdx.x & 7;                  // grid 1024
    int inner = blockIdx.x >> 3;               // 0..127
    int b = xcd >> 1;
    int su = (xcd & 1) * 128 + inner;          // 0..255 within batch
    int w = threadIdx.x >> 6;
    int wu = su * 4 + w;                       // 0..1023
    int mg = wu >> 4;                          // 64 groups of 4 mtiles
    int ns = wu & 15;                          // 16-way n-split
    int lane = threadIdx.x & 63;

    size_t boff = (size_t)b * (NN * HIDD);
    const u16b* thH = thetaH + boff; const u16b* thL = thetaL + boff;
    const u16b* phH = phiH + boff;   const u16b* phL = phiL + boff;

    s8v pBh[4][4], pBl[4][4];
#pragma unroll
    for (int mt = 0; mt < 4; mt++)
#pragma unroll
        for (int kb = 0; kb < 4; kb++) {
            int off = ((kb * 256 + (mg * 4 + mt)) * 64 + lane) * 8;
            pBh[mt][kb] = *reinterpret_cast<const s8v*>(phH + off);
            pBl[mt][kb] = *reinterpret_cast<const s8v*>(phL + off);
        }

    float Lp[4];
#pragma unroll
    for (int i = 0; i < 4; i++) Lp[i] = 0.f;

    for (int i = 0; i < 16; i++) {
        int ntile = ns * 16 + i;
        s8v tAh[4], tAl[4];
#pragma unroll
        for (int kb = 0; kb < 4; kb++) {
            int off = ((kb * 256 + ntile) * 64 + lane) * 8;
            tAh[kb] = *reinterpret_cast<const s8v*>(thH + off);
            tAl[kb] = *reinterpret_cast<const s8v*>(thL + off);
        }
#pragma unroll
        for (int mt = 0; mt < 4; mt++) {
            f4v shh = (f4v){0.f, 0.f, 0.f, 0.f};
            f4v sx  = (f4v){0.f, 0.f, 0.f, 0.f};
#pragma unroll
            for (int kb = 0; kb < 4; kb++)
                shh = __builtin_amdgcn_mfma_f32_16x16x32_bf16(tAh[kb], pBh[mt][kb], shh, 0, 0, 0);
#pragma unroll
            for (int kb = 0; kb < 4; kb++) {
                sx = __builtin_amdgcn_mfma_f32_16x16x32_bf16(tAh[kb], pBl[mt][kb], sx, 0, 0, 0);
                sx = __builtin_amdgcn_mfma_f32_16x16x32_bf16(tAl[kb], pBh[mt][kb], sx, 0, 0, 0);
            }
            Lp[mt] += (__expf(shh[0] + sx[0]) + __expf(shh[1] + sx[1]))
                    + (__expf(shh[2] + sx[2]) + __expf(shh[3] + sx[3]));
        }
    }
#pragma unroll
    for (int mt = 0; mt < 4; mt++) {
        float v = Lp[mt];
        v += __shfl_xor(v, 16);
        v += __shfl_xor(v, 32);
        if (lane < 16) atomicAdd(&Lraw[b * NN + (mg * 4 + mt) * 16 + lane], v);
    }
}

// ---------- Phase 2b: G'[m,o] = G[m,o] / L[m]  (in place, perm-swizzled) --------
__global__ __launch_bounds__(256) void rescale_kernel(
    u16b* __restrict__ gB, const float* __restrict__ Lraw)
{
    int t = blockIdx.x * 256 + threadIdx.x;    // grid 1024
    int flat0 = t * 8;
    int b = flat0 >> 19;
    int rem = flat0 & ((NN * HIDD) - 1);
    int kb = rem >> 12;
    int lane = (rem >> 3) & 63;
    int qs = lane >> 4;
    int mbase = kb * 32 + qs * 4;
    const float* Lp = Lraw + b * NN + mbase;
    u16b* gp = gB + flat0;
    s8v g = *reinterpret_cast<const s8v*>(gp);
    s8v o;
#pragma unroll
    for (int j = 0; j < 8; j++) {
        float v = b2f((unsigned short)g[j]) / Lp[((j >> 2) << 4) + (j & 3)];
        o[j] = (short)f2b(v);
    }
    *reinterpret_cast<s8v*>(gp) = o;
}

// ---------- small path Phase 3: Out += softmax(S) @ G', fused S^T recompute -----
__global__ __launch_bounds__(256, 2) void attn_kernel(
    const u16b* __restrict__ thetaH, const u16b* __restrict__ thetaL,
    const u16b* __restrict__ phiH, const u16b* __restrict__ phiL,
    const u16b* __restrict__ gB, float* __restrict__ outAcc)
{
    int xcd = blockIdx.x & 7;                  // grid 1024
    int inner = blockIdx.x >> 3;               // 0..127
    int combo = xcd * 4 + (inner & 3);         // 0..31 = b*8+ms (XCD-pinned)
    int b = combo >> 3;
    int ms = combo & 7;                        // 8-way m-split
    int ng = inner >> 2;                       // 0..31
    int w = threadIdx.x >> 6;
    int lane = threadIdx.x & 63;
    int l15 = lane & 15, q = lane >> 4;
    int ntile0 = ng * 8 + w * 2;

    size_t boff = (size_t)b * (NN * HIDD);
    const u16b* thH = thetaH + boff; const u16b* thL = thetaL + boff;
    const u16b* phH = phiH + boff;   const u16b* phL = phiL + boff;
    const u16b* gp = gB + boff;

    s8v tBh[2][4], tBl[2][4];
#pragma unroll
    for (int nt = 0; nt < 2; nt++)
#pragma unroll
        for (int kb = 0; kb < 4; kb++) {
            int off = ((kb * 256 + ntile0 + nt) * 64 + lane) * 8;
            tBh[nt][kb] = *reinterpret_cast<const s8v*>(thH + off);
            tBl[nt][kb] = *reinterpret_cast<const s8v*>(thL + off);
        }

    f4v acc[2][8];
#pragma unroll
    for (int nt = 0; nt < 2; nt++)
#pragma unroll
        for (int i = 0; i < 8; i++) acc[nt][i] = (f4v){0.f, 0.f, 0.f, 0.f};

    for (int mt = 0; mt < 16; mt++) {
        int m0 = ms * 512 + mt * 32;
        s8v pf[2];
#pragma unroll
        for (int h = 0; h < 2; h++) {
            int mtile = (m0 >> 4) + h;
            s8v pAh[4], pAl[4];
#pragma unroll
            for (int kb = 0; kb < 4; kb++) {
                int off = ((kb * 256 + mtile) * 64 + lane) * 8;
                pAh[kb] = *reinterpret_cast<const s8v*>(phH + off);
                pAl[kb] = *reinterpret_cast<const s8v*>(phL + off);
            }
#pragma unroll
            for (int nt = 0; nt < 2; nt++) {
                f4v shh = (f4v){0.f, 0.f, 0.f, 0.f};
                f4v sx  = (f4v){0.f, 0.f, 0.f, 0.f};
#pragma unroll
                for (int kb = 0; kb < 4; kb++)
                    shh = __builtin_amdgcn_mfma_f32_16x16x32_bf16(pAh[kb], tBh[nt][kb], shh, 0, 0, 0);
#pragma unroll
                for (int kb = 0; kb < 4; kb++) {
                    sx = __builtin_amdgcn_mfma_f32_16x16x32_bf16(pAh[kb], tBl[nt][kb], sx, 0, 0, 0);
                    sx = __builtin_amdgcn_mfma_f32_16x16x32_bf16(pAl[kb], tBh[nt][kb], sx, 0, 0, 0);
                }
#pragma unroll
                for (int r = 0; r < 4; r++)
                    pf[nt][h * 4 + r] = (short)f2b(__expf(shh[r] + sx[r]));
            }
        }
        int kb2 = m0 >> 5;
#pragma unroll
        for (int ot = 0; ot < 8; ot++) {
            s8v gf = *reinterpret_cast<const s8v*>(gp + ((kb2 * 8 + ot) * 64 + lane) * 8);
#pragma unroll
            for (int nt = 0; nt < 2; nt++)
                acc[nt][ot] = __builtin_amdgcn_mfma_f32_16x16x32_bf16(pf[nt], gf, acc[nt][ot], 0, 0, 0);
        }
    }

    float* oa = outAcc + (size_t)b * (NN * HIDD);
#pragma unroll
    for (int nt = 0; nt < 2; nt++) {
        int n_base = (ntile0 + nt) * 16;
#pragma unroll
        for (int ot = 0; ot < 8; ot++) {
#pragma unroll
            for (int r = 0; r < 4; r++) {
                int n = n_base + q * 4 + r;
                int o = ot * 16 + l15;
                atomicAdd(&oa[swz(o, n, NN / 16)], acc[nt][ot][r]);
            }
        }
    }
}

// ---------- big path Phase 2: S-pass -> P = e^s (A-frag layout) + L via LDS -----
// NO global atomics: per-wave LDS rows, then a private per-block Lpart slice.
__global__ __launch_bounds__(256, 2) void spass_kernel(
    const u16b* __restrict__ thetaH, const u16b* __restrict__ thetaL,
    const u16b* __restrict__ phiH, const u16b* __restrict__ phiL,
    u16b* __restrict__ P, float* __restrict__ Lpart)
{
    int xcd = blockIdx.x & 7;                  // grid 2048
    int inner = blockIdx.x >> 3;               // 0..255
    int combo = xcd * 8 + (inner & 7);         // 0..63 = b*16+ms
    int b = combo >> 4;
    int ms = combo & 15;                       // 16-way m-split
    int ng = inner >> 3;                       // 0..31
    int w = threadIdx.x >> 6;
    int lane = threadIdx.x & 63;
    int l15 = lane & 15, q = lane >> 4;
    int ntile0 = ng * 8 + w * 2;

    size_t boff = (size_t)b * (NN * HIDD);
    const u16b* thH = thetaH + boff; const u16b* thL = thetaL + boff;
    const u16b* phH = phiH + boff;   const u16b* phL = phiL + boff;
    u16b* Pb = P + (size_t)b * NN * NN;

    __shared__ float Lacc[4][256];             // [wave][m_local], each written once

    s8v tBh[2][4], tBl[2][4];
#pragma unroll
    for (int nt = 0; nt < 2; nt++)
#pragma unroll
        for (int kb = 0; kb < 4; kb++) {
            int off = ((kb * 256 + ntile0 + nt) * 64 + lane) * 8;
            tBh[nt][kb] = *reinterpret_cast<const s8v*>(thH + off);
            tBl[nt][kb] = *reinterpret_cast<const s8v*>(thL + off);
        }

    int ph = ng & 7;                           // stagger phase
    for (int mt = 0; mt < 8; mt++) {
        int mtr = (mt + ph) & 7;
        int m0 = ms * 256 + mtr * 32;
        float ev[2][2][4];
#pragma unroll
        for (int h = 0; h < 2; h++) {
            int mtile = (m0 >> 4) + h;
            s8v pAh[4], pAl[4];
#pragma unroll
            for (int kb = 0; kb < 4; kb++) {
                int off = ((kb * 256 + mtile) * 64 + lane) * 8;
                pAh[kb] = *reinterpret_cast<const s8v*>(phH + off);
                pAl[kb] = *reinterpret_cast<const s8v*>(phL + off);
            }
#pragma unroll
            for (int nt = 0; nt < 2; nt++) {
                f4v shh = (f4v){0.f, 0.f, 0.f, 0.f};
                f4v sx  = (f4v){0.f, 0.f, 0.f, 0.f};
#pragma unroll
                for (int kb = 0; kb < 4; kb++)
                    shh = __builtin_amdgcn_mfma_f32_16x16x32_bf16(pAh[kb], tBh[nt][kb], shh, 0, 0, 0);
#pragma unroll
                for (int kb = 0; kb < 4; kb++) {
                    sx = __builtin_amdgcn_mfma_f32_16x16x32_bf16(pAh[kb], tBl[nt][kb], sx, 0, 0, 0);
                    sx = __builtin_amdgcn_mfma_f32_16x16x32_bf16(pAl[kb], tBh[nt][kb], sx, 0, 0, 0);
                }
#pragma unroll
                for (int r = 0; r < 4; r++)
                    ev[nt][h][r] = __expf(shh[r] + sx[r]);
            }
        }
        // store P fragments
        int kb2 = m0 >> 5;
#pragma unroll
        for (int nt = 0; nt < 2; nt++) {
            s8v pf;
#pragma unroll
            for (int j = 0; j < 8; j++) pf[j] = (short)f2b(ev[nt][j >> 2][j & 3]);
            *reinterpret_cast<s8v*>(Pb + ((size_t)(kb2 * 256 + ntile0 + nt) * 64 + lane) * 8) = pf;
        }
        // column-sum over this wave's 32 n -> LDS (each m_local written exactly once)
        float cs[8];
#pragma unroll
        for (int j = 0; j < 8; j++) {
            cs[j] = ev[0][j >> 2][j & 3] + ev[1][j >> 2][j & 3];
            cs[j] += __shfl_xor(cs[j], 1);
            cs[j] += __shfl_xor(cs[j], 2);
            cs[j] += __shfl_xor(cs[j], 4);
            cs[j] += __shfl_xor(cs[j], 8);
        }
        if (l15 == 0) {
#pragma unroll
            for (int j = 0; j < 8; j++) {
                int ml = mtr * 32 + (j >> 2) * 16 + q * 4 + (j & 3);
                Lacc[w][ml] = cs[j];
            }
        }
    }
    __syncthreads();
    {
        int t = threadIdx.x;                   // 0..255 == m_local
        float s = (Lacc[0][t] + Lacc[1][t]) + (Lacc[2][t] + Lacc[3][t]);
        Lpart[((size_t)(combo * 32 + ng)) * 256 + t] = s;   // private slice, plain store
    }
}

// ---------- big path Phase 2a: Lraw[m] = sum over 32 Lpart slices ---------------
__global__ __launch_bounds__(256) void lsum_kernel(
    const float* __restrict__ Lpart, float* __restrict__ Lraw)
{
    int m = blockIdx.x * 256 + threadIdx.x;    // grid 64 -> 16384 m
    int combo = m >> 8;                        // b*16+ms
    int ml = m & 255;
    const float* base = Lpart + ((size_t)combo * 32) * 256 + ml;
    float s = 0.f;
#pragma unroll
    for (int ng = 0; ng < 32; ng++) s += base[ng * 256];
    Lraw[m] = s;
}

// ---------- big path Phase 3: partial[ms] = P-slice @ G' (NO atomics) -----------
// Depth-2 P prefetch keeps the L3-resident P stream in flight.
__global__ __launch_bounds__(256, 4) void pv_kernel(
    const u16b* __restrict__ P, const u16b* __restrict__ gB, u16b* __restrict__ pvPart)
{
    int xcd = blockIdx.x & 7;                  // grid 1024
    int inner = blockIdx.x >> 3;               // 0..127
    int combo = xcd * 2 + (inner & 1);         // 0..15 = b*4+ms (XCD-pinned)
    int b = combo >> 2;
    int ms = combo & 3;                        // 4-way m-split
    int ng = inner >> 1;                       // 0..63
    int w = threadIdx.x >> 6;
    int lane = threadIdx.x & 63;
    int l15 = lane & 15, q = lane >> 4;
    int ntile = ng * 4 + w;                    // 0..255, one ntile per wave

    const u16b* Pb = P + (size_t)b * NN * NN;
    const u16b* gp = gB + (size_t)b * (NN * HIDD);

    f4v acc[8];
#pragma unroll
    for (int i = 0; i < 8; i++) acc[i] = (f4v){0.f, 0.f, 0.f, 0.f};

    int ph = ng & 31;                          // stagger phase
    int k0 = ms * 32 + ph;
    int k1 = ms * 32 + ((ph + 1) & 31);
    s8v pcur = *reinterpret_cast<const s8v*>(Pb + ((size_t)(k0 * 256 + ntile) * 64 + lane) * 8);
    s8v pnx1 = *reinterpret_cast<const s8v*>(Pb + ((size_t)(k1 * 256 + ntile) * 64 + lane) * 8);

    for (int it = 0; it < 32; it++) {
        int kb2  = ms * 32 + ((it + ph) & 31);
        int kb2n = ms * 32 + ((it + 2 + ph) & 31);
        s8v pnx2 = *reinterpret_cast<const s8v*>(Pb + ((size_t)(kb2n * 256 + ntile) * 64 + lane) * 8);
#pragma unroll
        for (int ot = 0; ot < 8; ot++) {
            s8v gf = *reinterpret_cast<const s8v*>(gp + ((kb2 * 8 + ot) * 64 + lane) * 8);
            acc[ot] = __builtin_amdgcn_mfma_f32_16x16x32_bf16(pcur, gf, acc[ot], 0, 0, 0);
        }
        pcur = pnx1;
        pnx1 = pnx2;
    }

    u16b* pp = pvPart + (size_t)ms * ((size_t)BB * NN * HIDD) + (size_t)b * (NN * HIDD);
    int n_base = ntile * 16;
#pragma unroll
    for (int ot = 0; ot < 8; ot++) {
#pragma unroll
        for (int r = 0; r < 4; r++) {
            int n = n_base + q * 4 + r;
            int o = ot * 16 + l15;
            pp[swz(o, n, NN / 16)] = f2b(acc[ot][r]);
        }
    }
}

// ---------- big path Phase 4: y = x + w_mask @ (sum of partials)^T --------------
__global__ __launch_bounds__(256) void final_big_kernel(
    const float* __restrict__ x, const u16b* __restrict__ wmH, const u16b* __restrict__ wmL,
    const u16b* __restrict__ pvPart, float* __restrict__ y)
{
    int wave = blockIdx.x * 4 + (threadIdx.x >> 6);   // 4096 waves
    int lane = threadIdx.x & 63;
    int l15 = lane & 15, q = lane >> 4;
    int b = wave >> 10;
    int rem = wave & 1023;
    int ctile = rem >> 6;
    int n64 = rem & 63;
    const size_t pstride = (size_t)BB * NN * HIDD;
    const u16b* pb = pvPart + (size_t)b * (NN * HIDD);
    const float* xb = x + (size_t)b * CC * NN;
    float* yb = y + (size_t)b * CC * NN;
    int c0 = ctile * 16;

    s8v aH[4], aL[4];
#pragma unroll
    for (int kb = 0; kb < 4; kb++) {
        int off = (c0 + l15) * HIDD + kb * 32 + q * 8;
        aH[kb] = *reinterpret_cast<const s8v*>(wmH + off);
        aL[kb] = *reinterpret_cast<const s8v*>(wmL + off);
    }

#pragma unroll
    for (int nt = 0; nt < 4; nt++) {
        int ntile = n64 * 4 + nt;
        f4v acc = (f4v){0.f, 0.f, 0.f, 0.f};
#pragma unroll
        for (int kb = 0; kb < 4; kb++) {
            size_t fo = ((size_t)(kb * 256 + ntile) * 64 + lane) * 8;
            float s[8];
#pragma unroll
            for (int j = 0; j < 8; j++) s[j] = 0.f;
#pragma unroll
            for (int p = 0; p < 4; p++) {
                s8v v = *reinterpret_cast<const s8v*>(pb + p * pstride + fo);
#pragma unroll
                for (int j = 0; j < 8; j++) s[j] += b2f((unsigned short)v[j]);
            }
            s8v bhv, blv;
#pragma unroll
            for (int j = 0; j < 8; j++) {
                short h, l;
                split2(s[j], h, l);
                bhv[j] = h; blv[j] = l;
            }
            acc = __builtin_amdgcn_mfma_f32_16x16x32_bf16(aH[kb], bhv, acc, 0, 0, 0);
            acc = __builtin_amdgcn_mfma_f32_16x16x32_bf16(aH[kb], blv, acc, 0, 0, 0);
            acc = __builtin_amdgcn_mfma_f32_16x16x32_bf16(aL[kb], bhv, acc, 0, 0, 0);
        }
#pragma unroll
        for (int r = 0; r < 4; r++) {
            int c = c0 + q * 4 + r;
            int n = ntile * 16 + l15;
            size_t idx = (size_t)c * NN + n;
            yb[idx] = xb[idx] + acc[r];
        }
    }
}

// ---------- small path Phase 4: y = x + w_mask @ Out^T --------------------------
__global__ __launch_bounds__(256) void final_kernel(
    const float* __restrict__ x, const u16b* __restrict__ wmH, const u16b* __restrict__ wmL,
    const float* __restrict__ outAcc, float* __restrict__ y)
{
    int wave = blockIdx.x * 4 + (threadIdx.x >> 6);   // 4096 waves
    int lane = threadIdx.x & 63;
    int l15 = lane & 15, q = lane >> 4;
    int b = wave >> 10;
    int rem = wave & 1023;
    int ctile = rem >> 6;
    int n64 = rem & 63;
    const float* oa = outAcc + (size_t)b * (NN * HIDD);
    const float* xb = x + (size_t)b * CC * NN;
    float* yb = y + (size_t)b * CC * NN;
    int c0 = ctile * 16;

    s8v aH[4], aL[4];
#pragma unroll
    for (int kb = 0; kb < 4; kb++) {
        int off = (c0 + l15) * HIDD + kb * 32 + q * 8;
        aH[kb] = *reinterpret_cast<const s8v*>(wmH + off);
        aL[kb] = *reinterpret_cast<const s8v*>(wmL + off);
    }

#pragma unroll
    for (int nt = 0; nt < 4; nt++) {
        int ntile = n64 * 4 + nt;
        f4v acc = (f4v){0.f, 0.f, 0.f, 0.f};
#pragma unroll
        for (int kb = 0; kb < 4; kb++) {
            const float* bp = oa + ((size_t)(kb * 256 + ntile) * 64 + lane) * 8;
            f4v b0 = *reinterpret_cast<const f4v*>(bp);
            f4v b1 = *reinterpret_cast<const f4v*>(bp + 4);
            s8v bhv, blv;
#pragma unroll
            for (int j = 0; j < 4; j++) {
                short h, l;
                split2(b0[j], h, l); bhv[j] = h; blv[j] = l;
                split2(b1[j], h, l); bhv[j + 4] = h; blv[j + 4] = l;
            }
            acc = __builtin_amdgcn_mfma_f32_16x16x32_bf16(aH[kb], bhv, acc, 0, 0, 0);
            acc = __builtin_amdgcn_mfma_f32_16x16x32_bf16(aH[kb], blv, acc, 0, 0, 0);
            acc = __builtin_amdgcn_mfma_f32_16x16x32_bf16(aL[kb], bhv, acc, 0, 0, 0);
        }
#pragma unroll
        for (int r = 0; r < 4; r++) {
            int c = c0 + q * 4 + r;
            int n = ntile * 16 + l15;
            size_t idx = (size_t)c * NN + n;
            yb[idx] = xb[idx] + acc[r];
        }
    }
}

extern "C" void kernel_launch(void* const* d_in, const int* in_sizes, int n_in,
                              void* d_out, int out_size, void* d_ws, size_t ws_size,
                              hipStream_t stream)
{
    (void)in_sizes; (void)n_in; (void)out_size;
    const float* x  = (const float*)d_in[0];
    const float* wt = (const float*)d_in[1];
    const float* wp = (const float*)d_in[2];
    const float* wg = (const float*)d_in[3];
    const float* wm = (const float*)d_in[4];
    float* y = (float*)d_out;

    char* ws = (char*)d_ws;
    const size_t MB = 1 << 20;
    u16b* thetaH = (u16b*)(ws + 0 * MB);
    u16b* thetaL = (u16b*)(ws + 4 * MB);
    u16b* phiH   = (u16b*)(ws + 8 * MB);
    u16b* phiL   = (u16b*)(ws + 12 * MB);
    u16b* pvPart = (u16b*)(ws + 0 * MB);                   // 16 MB, overlays theta/phi
    u16b* gB     = (u16b*)(ws + 16 * MB);
    float* outAcc = (float*)(ws + 20 * MB);                // 8 MB fp32 (small path)
    float* Lraw   = (float*)(ws + 28 * MB);                // 64 KB
    char* wbase = ws + 28 * MB + (64 << 10);
    u16b* wHb = (u16b*)(wbase);                            // 128 KB
    u16b* wLb = (u16b*)(wbase + (128 << 10));              // 128 KB
    u16b* wgB = (u16b*)(wbase + (256 << 10));              // 64 KB
    u16b* wmH = (u16b*)(wbase + (320 << 10));              // 64 KB
    u16b* wmL = (u16b*)(wbase + (384 << 10));              // 64 KB
    float* Lpart = (float*)(ws + 30 * MB);                 // 2 MB (big path)
    u16b* P   = (u16b*)(ws + 32 * MB);                     // 134.2 MB (big path)

    const size_t need_big = 32 * MB + (size_t)BB * NN * NN * sizeof(u16b);
    const bool big = ws_size >= need_big;

    hipLaunchKernelGGL(prep_kernel, dim3(128), dim3(256), 0, stream,
                       wt, wp, wg, wm, wHb, wLb, wgB, wmH, wmL);
    hipLaunchKernelGGL(proj_kernel, dim3(512), dim3(256), 0, stream,
                       x, wHb, wLb, wgB, thetaH, thetaL, phiH, phiL, gB);

    if (big) {
        hipLaunchKernelGGL(spass_kernel,   dim3(2048), dim3(256), 0, stream,
                           thetaH, thetaL, phiH, phiL, P, Lpart);
        hipLaunchKernelGGL(lsum_kernel,    dim3(64),   dim3(256), 0, stream, Lpart, Lraw);
        hipLaunchKernelGGL(rescale_kernel, dim3(1024), dim3(256), 0, stream, gB, Lraw);
        // pv overwrites the theta/phi region (dead after spass) with bf16 partials
        hipLaunchKernelGGL(pv_kernel,      dim3(1024), dim3(256), 0, stream, P, gB, pvPart);
        hipLaunchKernelGGL(final_big_kernel, dim3(1024), dim3(256), 0, stream,
                           x, wmH, wmL, pvPart, y);
    } else {
        hipMemsetAsync(Lraw, 0, (size_t)BB * NN * sizeof(float), stream);
        hipMemsetAsync(outAcc, 0, (size_t)BB * NN * HIDD * sizeof(float), stream);
        hipLaunchKernelGGL(stats_kernel,   dim3(1024), dim3(256), 0, stream,
                           thetaH, thetaL, phiH, phiL, Lraw);
        hipLaunchKernelGGL(rescale_kernel, dim3(1024), dim3(256), 0, stream, gB, Lraw);
        hipLaunchKernelGGL(attn_kernel,    dim3(1024), dim3(256), 0, stream,
                           thetaH, thetaL, phiH, phiL, gB, outAcc);
        hipLaunchKernelGGL(final_kernel,   dim3(1024), dim3(256), 0, stream,
                           x, wmH, wmL, outAcc, y);
    }
}